// Round 2
// baseline (2707.091 us; speedup 1.0000x reference)
//
#include <hip/hip_runtime.h>

#define LRELU(x) ((x) > 0.0f ? (x) : 0.2f * (x))

// ---------------------------------------------------------------------------
// conv0: img (B,1,128,128) -> x0 (B,64,64,64), k4 s2 p1, +bias, +leaky
// grid (B*64, 16), block 256
__global__ __launch_bounds__(256) void k_conv0(
    const float* __restrict__ img, const float* __restrict__ w0,
    const float* __restrict__ b0, const int* __restrict__ sidx,
    float* __restrict__ x0) {
  int bc = blockIdx.x;
  int b = bc >> 6, co = bc & 63;
  int pix = blockIdx.y * 256 + threadIdx.x;  // 0..4095
  int oh = pix >> 6, ow = pix & 63;
  int s = sidx[b];
  const float* w = w0 + (s * 64 + co) * 16;
  float wr[16];
#pragma unroll
  for (int i = 0; i < 16; i++) wr[i] = w[i];
  float acc = b0[s * 64 + co];
  const float* ip = img + (size_t)b * 128 * 128;
  int ih0 = oh * 2 - 1, iw0 = ow * 2 - 1;
#pragma unroll
  for (int kh = 0; kh < 4; kh++) {
    int ih = ih0 + kh;
    if ((unsigned)ih >= 128u) continue;
#pragma unroll
    for (int kw = 0; kw < 4; kw++) {
      int iw = iw0 + kw;
      if ((unsigned)iw >= 128u) continue;
      acc += wr[kh * 4 + kw] * ip[ih * 128 + iw];
    }
  }
  x0[(((size_t)b * 64 + co) << 12) + pix] = LRELU(acc);
}

// ---------------------------------------------------------------------------
// conv1: x0 (B,64,64,64) -> x1 raw (B,128,32,32), k4 s2 p1, +bias (no act yet)
// grid (B*128, 4), block 256; weights staged in LDS (64*16 floats)
__global__ __launch_bounds__(256) void k_conv1(
    const float* __restrict__ x0, const float* __restrict__ w1,
    const float* __restrict__ b1, const int* __restrict__ sidx,
    float* __restrict__ x1) {
  __shared__ float wsh[1024];
  int bc = blockIdx.x;
  int b = bc >> 7, co = bc & 127;
  int s = sidx[b];
  const float* w = w1 + ((size_t)(s * 128 + co)) * 1024;
  for (int i = threadIdx.x; i < 1024; i += 256) wsh[i] = w[i];
  __syncthreads();
  int pix = blockIdx.y * 256 + threadIdx.x;  // 0..1023
  int oh = pix >> 5, ow = pix & 31;
  float acc = b1[s * 128 + co];
  int ih0 = oh * 2 - 1, iw0 = ow * 2 - 1;
  const float* xin = x0 + (size_t)b * 64 * 4096;
  for (int ci = 0; ci < 64; ci++) {
    const float* xp = xin + ci * 4096;
    const float* wp = wsh + ci * 16;
#pragma unroll
    for (int kh = 0; kh < 4; kh++) {
      int ih = ih0 + kh;
      if ((unsigned)ih >= 64u) continue;
#pragma unroll
      for (int kw = 0; kw < 4; kw++) {
        int iw = iw0 + kw;
        if ((unsigned)iw >= 64u) continue;
        acc += wp[kh * 4 + kw] * xp[ih * 64 + iw];
      }
    }
  }
  x1[(((size_t)b * 128 + co) << 10) + pix] = acc;
}

// ---------------------------------------------------------------------------
// instance norm (+leaky) in place. One block per (b,c); NPIX elements.
template <int NPIX>
__global__ __launch_bounds__(256) void k_inorm(float* __restrict__ x) {
  float* p = x + (size_t)blockIdx.x * NPIX;
  float sum = 0.0f, sq = 0.0f;
  for (int i = threadIdx.x; i < NPIX; i += 256) {
    float v = p[i];
    sum += v;
    sq += v * v;
  }
#pragma unroll
  for (int o = 32; o > 0; o >>= 1) {
    sum += __shfl_down(sum, o, 64);
    sq += __shfl_down(sq, o, 64);
  }
  __shared__ float red[8];
  int wid = threadIdx.x >> 6;
  if ((threadIdx.x & 63) == 0) {
    red[wid] = sum;
    red[4 + wid] = sq;
  }
  __syncthreads();
  if (threadIdx.x == 0) {
    red[0] = red[0] + red[1] + red[2] + red[3];
    red[4] = red[4] + red[5] + red[6] + red[7];
  }
  __syncthreads();
  float m = red[0] * (1.0f / NPIX);
  float var = red[4] * (1.0f / NPIX) - m * m;
  float inv = rsqrtf(var + 1e-5f);
  for (int i = threadIdx.x; i < NPIX; i += 256) {
    float v = (p[i] - m) * inv;
    p[i] = LRELU(v);
  }
}

// ---------------------------------------------------------------------------
// 1x1 conv: out (B,CO,1024) = w (S,CO,128) @ x (B,128,1024) + bias
// grid (B*CO), block 256, each thread 4 n's
__global__ __launch_bounds__(256) void k_conv1x1(
    const float* __restrict__ xin, const float* __restrict__ w,
    const float* __restrict__ bias, const int* __restrict__ sidx,
    float* __restrict__ out, int CO) {
  __shared__ float wsh[128];
  int bc = blockIdx.x;
  int b = bc / CO, co = bc % CO;
  int s = sidx[b];
  if (threadIdx.x < 128) wsh[threadIdx.x] = w[((size_t)(s * CO + co)) * 128 + threadIdx.x];
  __syncthreads();
  float bb = bias[s * CO + co];
  const float* xp = xin + (size_t)b * 128 * 1024;
#pragma unroll
  for (int j = 0; j < 4; j++) {
    int n = threadIdx.x + (j << 8);
    float acc = bb;
    for (int ci = 0; ci < 128; ci++) acc += wsh[ci] * xp[(ci << 10) + n];
    out[((size_t)b * CO + co) * 1024 + n] = acc;
  }
}

// ---------------------------------------------------------------------------
// fused self-attention: scores+softmax+PV per (b, 8-n tile), y = gamma*out + x1
// grid (B*128), block 256. LDS scores [8][1025] fp32 (~33 KB).
__global__ __launch_bounds__(256) void k_attn(
    const float* __restrict__ q, const float* __restrict__ k, const float* __restrict__ v,
    const float* __restrict__ x1, const float* __restrict__ gamma,
    const int* __restrict__ sidx, float* __restrict__ y) {
  __shared__ float sc[8 * 1025];
  __shared__ float ql[16 * 8];
  __shared__ float inv_s[8];
  int b = blockIdx.x >> 7;
  int n0 = (blockIdx.x & 127) << 3;
  const float* qb = q + (size_t)b * 16 * 1024;
  const float* kb = k + (size_t)b * 16 * 1024;
  const float* vb = v + (size_t)b * 128 * 1024;
  const float* xb = x1 + (size_t)b * 128 * 1024;
  if (threadIdx.x < 128) {
    int c = threadIdx.x >> 3, nl = threadIdx.x & 7;
    ql[c * 8 + nl] = qb[(c << 10) + n0 + nl];
  }
  __syncthreads();
  // scores: sc[nl][m] = sum_c q[c,n0+nl]*k[c,m]; coalesced k reads
#pragma unroll 1
  for (int i = 0; i < 32; i++) {
    int nl = i >> 2;
    int m = ((i & 3) << 8) + threadIdx.x;
    float a = 0.0f;
#pragma unroll
    for (int c = 0; c < 16; c++) a += ql[c * 8 + nl] * kb[(c << 10) + m];
    sc[nl * 1025 + m] = a;
  }
  __syncthreads();
  // softmax per row: 8 rows x 32 lanes
  {
    int nl = threadIdx.x >> 5, l = threadIdx.x & 31;
    float* row = sc + nl * 1025;
    float mx = -1e30f;
    for (int m = l; m < 1024; m += 32) mx = fmaxf(mx, row[m]);
#pragma unroll
    for (int o = 16; o > 0; o >>= 1) mx = fmaxf(mx, __shfl_xor(mx, o, 64));
    float ssum = 0.0f;
    for (int m = l; m < 1024; m += 32) {
      float e = __expf(row[m] - mx);
      row[m] = e;
      ssum += e;
    }
#pragma unroll
    for (int o = 16; o > 0; o >>= 1) ssum += __shfl_xor(ssum, o, 64);
    if (l == 0) inv_s[nl] = 1.0f / ssum;
  }
  __syncthreads();
  float g = gamma[sidx[b]];
  // PV: co = tid&127 (coalesced v reads, broadcast sc reads), nl = tid>>7 + 2j
#pragma unroll
  for (int j = 0; j < 4; j++) {
    int oi = threadIdx.x + (j << 8);
    int co = oi & 127, nl = oi >> 7;
    const float* vp = vb + ((size_t)co << 10);
    const float* row = sc + nl * 1025;
    float acc = 0.0f;
    for (int m = 0; m < 1024; m++) acc += vp[m] * row[m];
    int n = n0 + nl;
    y[(((size_t)b * 128 + co) << 10) + n] = g * acc * inv_s[nl] + xb[(co << 10) + n];
  }
}

// ---------------------------------------------------------------------------
// conv2: y (B,128,32,32) -> x2 raw (B,256,16,16), k4 s2 p1, +bias
// grid (B*256), block 256 (one thread per output pixel); weights in LDS (2048)
__global__ __launch_bounds__(256) void k_conv2(
    const float* __restrict__ y, const float* __restrict__ w2,
    const float* __restrict__ b2, const int* __restrict__ sidx,
    float* __restrict__ x2) {
  __shared__ float wsh[2048];
  int bc = blockIdx.x;
  int b = bc >> 8, co = bc & 255;
  int s = sidx[b];
  const float* w = w2 + ((size_t)(s * 256 + co)) * 2048;
  for (int i = threadIdx.x; i < 2048; i += 256) wsh[i] = w[i];
  __syncthreads();
  int pix = threadIdx.x;
  int oh = pix >> 4, ow = pix & 15;
  float acc = b2[s * 256 + co];
  int ih0 = oh * 2 - 1, iw0 = ow * 2 - 1;
  const float* xin = y + (size_t)b * 128 * 1024;
  for (int ci = 0; ci < 128; ci++) {
    const float* xp = xin + (ci << 10);
    const float* wp = wsh + (ci << 4);
#pragma unroll
    for (int kh = 0; kh < 4; kh++) {
      int ih = ih0 + kh;
      if ((unsigned)ih >= 32u) continue;
#pragma unroll
      for (int kw = 0; kw < 4; kw++) {
        int iw = iw0 + kw;
        if ((unsigned)iw >= 32u) continue;
        acc += wp[kh * 4 + kw] * xp[(ih << 5) + iw];
      }
    }
  }
  x2[(((size_t)b * 256 + co) << 8) + pix] = acc;
}

// ---------------------------------------------------------------------------
// head: x2 (B,256,16,16) -> out (B,1,15,15), k4 s1 p1, +bias
// grid (B*225), block 256 (one thread per input channel), block-reduce
__global__ __launch_bounds__(256) void k_head(
    const float* __restrict__ x2, const float* __restrict__ wh,
    const float* __restrict__ bh, const int* __restrict__ sidx,
    float* __restrict__ out) {
  int bp = blockIdx.x;
  int b = bp / 225, pix = bp % 225;
  int oh = pix / 15, ow = pix % 15;
  int s = sidx[b];
  int ci = threadIdx.x;
  const float* xp = x2 + (((size_t)b * 256 + ci) << 8);
  const float* wp = wh + s * 4096 + ci * 16;
  float acc = 0.0f;
#pragma unroll
  for (int kh = 0; kh < 4; kh++) {
    int ih = oh - 1 + kh;
    if ((unsigned)ih >= 16u) continue;
#pragma unroll
    for (int kw = 0; kw < 4; kw++) {
      int iw = ow - 1 + kw;
      if ((unsigned)iw >= 16u) continue;
      acc += wp[kh * 4 + kw] * xp[(ih << 4) + iw];
    }
  }
#pragma unroll
  for (int o = 32; o > 0; o >>= 1) acc += __shfl_down(acc, o, 64);
  __shared__ float red[4];
  if ((threadIdx.x & 63) == 0) red[threadIdx.x >> 6] = acc;
  __syncthreads();
  if (threadIdx.x == 0) {
    float r = red[0] + red[1] + red[2] + red[3] + bh[s];
    out[b * 225 + pix] = r;
  }
}

// ---------------------------------------------------------------------------
extern "C" void kernel_launch(void* const* d_in, const int* in_sizes, int n_in,
                              void* d_out, int out_size, void* d_ws, size_t ws_size,
                              hipStream_t stream) {
  const float* img = (const float*)d_in[0];
  const int* sidx = (const int*)d_in[1];
  const float* w0 = (const float*)d_in[2];
  const float* b0 = (const float*)d_in[3];
  const float* w1 = (const float*)d_in[4];
  const float* b1 = (const float*)d_in[5];
  const float* w2 = (const float*)d_in[6];
  const float* b2 = (const float*)d_in[7];
  const float* wq = (const float*)d_in[8];
  const float* bq = (const float*)d_in[9];
  const float* wk = (const float*)d_in[10];
  const float* bk = (const float*)d_in[11];
  const float* wv = (const float*)d_in[12];
  const float* bv = (const float*)d_in[13];
  const float* gamma = (const float*)d_in[14];
  const float* wh = (const float*)d_in[15];
  const float* bh = (const float*)d_in[16];
  float* out = (float*)d_out;

  float* ws = (float*)d_ws;
  // workspace layout (floats); y aliases x0 (x0 dead after conv1)
  float* x0 = ws + 0;        // 4,194,304  (B,64,64,64)
  float* x1 = ws + 4194304;  // 2,097,152  (B,128,32,32)
  float* q = ws + 6291456;   // 262,144    (B,16,1024)
  float* k = ws + 6553600;   // 262,144
  float* v = ws + 6815744;   // 2,097,152  (B,128,1024)
  float* x2 = ws + 8912896;  // 1,048,576  (B,256,16,16)
  float* y = x0;             // (B,128,1024) alias

  const int B = 16;

  k_conv0<<<dim3(B * 64, 16), 256, 0, stream>>>(img, w0, b0, sidx, x0);
  k_conv1<<<dim3(B * 128, 4), 256, 0, stream>>>(x0, w1, b1, sidx, x1);
  k_inorm<1024><<<B * 128, 256, 0, stream>>>(x1);
  k_conv1x1<<<B * 16, 256, 0, stream>>>(x1, wq, bq, sidx, q, 16);
  k_conv1x1<<<B * 16, 256, 0, stream>>>(x1, wk, bk, sidx, k, 16);
  k_conv1x1<<<B * 128, 256, 0, stream>>>(x1, wv, bv, sidx, v, 128);
  k_attn<<<B * 128, 256, 0, stream>>>(q, k, v, x1, gamma, sidx, y);
  k_conv2<<<B * 256, 256, 0, stream>>>(y, w2, b2, sidx, x2);
  k_inorm<256><<<B * 256, 256, 0, stream>>>(x2);
  k_head<<<B * 225, 256, 0, stream>>>(x2, wh, bh, sidx, out);
}

// Round 3
// 773.979 us; speedup vs baseline: 3.4976x; 3.4976x over previous
//
#include <hip/hip_runtime.h>

#define LRELU(x) ((x) > 0.0f ? (x) : 0.2f * (x))

// ---------------------------------------------------------------------------
// conv0: img (B,1,128,128) -> x0 (B,64,64,64), k4 s2 p1, +bias, +leaky
// grid (B*64, 16), block 256
__global__ __launch_bounds__(256) void k_conv0(
    const float* __restrict__ img, const float* __restrict__ w0,
    const float* __restrict__ b0, const int* __restrict__ sidx,
    float* __restrict__ x0) {
  int bc = blockIdx.x;
  int b = bc >> 6, co = bc & 63;
  int pix = blockIdx.y * 256 + threadIdx.x;  // 0..4095
  int oh = pix >> 6, ow = pix & 63;
  int s = sidx[b];
  const float* w = w0 + (s * 64 + co) * 16;
  float wr[16];
#pragma unroll
  for (int i = 0; i < 16; i++) wr[i] = w[i];
  float acc = b0[s * 64 + co];
  const float* ip = img + (size_t)b * 128 * 128;
  int ih0 = oh * 2 - 1, iw0 = ow * 2 - 1;
#pragma unroll
  for (int kh = 0; kh < 4; kh++) {
    int ih = ih0 + kh;
    if ((unsigned)ih >= 128u) continue;
#pragma unroll
    for (int kw = 0; kw < 4; kw++) {
      int iw = iw0 + kw;
      if ((unsigned)iw >= 128u) continue;
      acc += wr[kh * 4 + kw] * ip[ih * 128 + iw];
    }
  }
  x0[(((size_t)b * 64 + co) << 12) + pix] = LRELU(acc);
}

// ---------------------------------------------------------------------------
// conv1: x0 (B,64,64,64) -> x1 raw (B,128,32,32), k4 s2 p1, +bias
// grid (B, 32): block handles batch b, 4 co's; thread: 4 pixels x 4 co.
// LDS: 2 input channel slabs with zero halo (66x66), weights 4co x 2ci x 16.
__global__ __launch_bounds__(256) void k_conv1(
    const float* __restrict__ x0, const float* __restrict__ w1,
    const float* __restrict__ b1, const int* __restrict__ sidx,
    float* __restrict__ x1) {
  __shared__ float ysh[2 * 4356];  // 66*66 = 4356 per ci slab
  __shared__ float wsh[128];       // [c][2ci*16]
  const int t = threadIdx.x;
  const int b = blockIdx.x, co0 = blockIdx.y * 4;
  const int s = sidx[b];
  for (int i = t; i < 2 * 4356; i += 256) ysh[i] = 0.0f;  // zero halo once
  float acc[4][4];  // [j pix][c co]
#pragma unroll
  for (int c = 0; c < 4; c++) {
    float bb = b1[s * 128 + co0 + c];
#pragma unroll
    for (int j = 0; j < 4; j++) acc[j][c] = bb;
  }
  const float* xb = x0 + (size_t)b * 64 * 4096;
  const float* wb = w1 + ((size_t)(s * 128 + co0)) * 1024;
  __syncthreads();
  for (int cc = 0; cc < 32; cc++) {  // 2 ci per chunk
#pragma unroll
    for (int i = 0; i < 32; i++) {
      int idx = (i << 8) + t;
      int ci = idx >> 12, p = idx & 4095;
      int ih = p >> 6, iw = p & 63;
      ysh[ci * 4356 + (ih + 1) * 66 + (iw + 1)] = xb[((cc * 2 + ci) << 12) + p];
    }
    if (t < 128) wsh[t] = wb[(t >> 5) * 1024 + cc * 32 + (t & 31)];
    __syncthreads();
#pragma unroll
    for (int ci = 0; ci < 2; ci++) {
      float wr[64];  // all 4co x 16 taps in regs
#pragma unroll
      for (int u = 0; u < 64; u++) wr[u] = wsh[(u >> 4) * 32 + ci * 16 + (u & 15)];
#pragma unroll
      for (int j = 0; j < 4; j++) {
        int pix = t + (j << 8);
        int oh = pix >> 5, ow = pix & 31;
        const float* yp = ysh + ci * 4356 + (oh * 2) * 66 + ow * 2;
        float yv[16];
#pragma unroll
        for (int kh = 0; kh < 4; kh++)
#pragma unroll
          for (int kw = 0; kw < 4; kw++) yv[kh * 4 + kw] = yp[kh * 66 + kw];
#pragma unroll
        for (int c = 0; c < 4; c++)
#pragma unroll
          for (int u = 0; u < 16; u++) acc[j][c] += wr[c * 16 + u] * yv[u];
      }
    }
    __syncthreads();
  }
#pragma unroll
  for (int c = 0; c < 4; c++)
#pragma unroll
    for (int j = 0; j < 4; j++)
      x1[(((size_t)b * 128 + co0 + c) << 10) + t + (j << 8)] = acc[j][c];
}

// ---------------------------------------------------------------------------
// instance norm (+leaky) in place. One block per (b,c); NPIX elements.
template <int NPIX>
__global__ __launch_bounds__(256) void k_inorm(float* __restrict__ x) {
  float* p = x + (size_t)blockIdx.x * NPIX;
  float sum = 0.0f, sq = 0.0f;
  for (int i = threadIdx.x; i < NPIX; i += 256) {
    float v = p[i];
    sum += v;
    sq += v * v;
  }
#pragma unroll
  for (int o = 32; o > 0; o >>= 1) {
    sum += __shfl_down(sum, o, 64);
    sq += __shfl_down(sq, o, 64);
  }
  __shared__ float red[8];
  int wid = threadIdx.x >> 6;
  if ((threadIdx.x & 63) == 0) {
    red[wid] = sum;
    red[4 + wid] = sq;
  }
  __syncthreads();
  if (threadIdx.x == 0) {
    red[0] = red[0] + red[1] + red[2] + red[3];
    red[4] = red[4] + red[5] + red[6] + red[7];
  }
  __syncthreads();
  float m = red[0] * (1.0f / NPIX);
  float var = red[4] * (1.0f / NPIX) - m * m;
  float inv = rsqrtf(var + 1e-5f);
  for (int i = threadIdx.x; i < NPIX; i += 256) {
    float v = (p[i] - m) * inv;
    p[i] = LRELU(v);
  }
}

// ---------------------------------------------------------------------------
// 1x1 conv: out (B,CO,1024) = w (S,CO,128) @ x (B,128,1024) + bias
__global__ __launch_bounds__(256) void k_conv1x1(
    const float* __restrict__ xin, const float* __restrict__ w,
    const float* __restrict__ bias, const int* __restrict__ sidx,
    float* __restrict__ out, int CO) {
  __shared__ float wsh[128];
  int bc = blockIdx.x;
  int b = bc / CO, co = bc % CO;
  int s = sidx[b];
  if (threadIdx.x < 128) wsh[threadIdx.x] = w[((size_t)(s * CO + co)) * 128 + threadIdx.x];
  __syncthreads();
  float bb = bias[s * CO + co];
  const float* xp = xin + (size_t)b * 128 * 1024;
#pragma unroll
  for (int j = 0; j < 4; j++) {
    int n = threadIdx.x + (j << 8);
    float acc = bb;
    for (int ci = 0; ci < 128; ci++) acc += wsh[ci] * xp[(ci << 10) + n];
    out[((size_t)b * CO + co) * 1024 + n] = acc;
  }
}

// ---------------------------------------------------------------------------
// fused self-attention per (b, 8-n tile): scores+softmax in LDS, then PV with
// v staged in LDS tiles (coalesced), y = gamma*out + x1. grid (B*128), block 256.
__global__ __launch_bounds__(256) void k_attn(
    const float* __restrict__ q, const float* __restrict__ k, const float* __restrict__ v,
    const float* __restrict__ x1, const float* __restrict__ gamma,
    const int* __restrict__ sidx, float* __restrict__ y) {
  __shared__ float sc[8 * 1025];
  __shared__ float vt[128 * 33];  // 128 co x 32 m tile, pad 33
  __shared__ float ql[16 * 8];
  __shared__ float inv_s[8];
  const int t = threadIdx.x;
  int b = blockIdx.x >> 7;
  int n0 = (blockIdx.x & 127) << 3;
  const float* qb = q + (size_t)b * 16 * 1024;
  const float* kb = k + (size_t)b * 16 * 1024;
  const float* vb = v + (size_t)b * 128 * 1024;
  const float* xb = x1 + (size_t)b * 128 * 1024;
  if (t < 128) {
    int c = t >> 3, nl = t & 7;
    ql[c * 8 + nl] = qb[(c << 10) + n0 + nl];
  }
  __syncthreads();
  // scores: sc[nl][m] = sum_c q[c,n0+nl]*k[c,m]; coalesced k reads
#pragma unroll 1
  for (int i = 0; i < 32; i++) {
    int nl = i >> 2;
    int m = ((i & 3) << 8) + t;
    float a = 0.0f;
#pragma unroll
    for (int c = 0; c < 16; c++) a += ql[c * 8 + nl] * kb[(c << 10) + m];
    sc[nl * 1025 + m] = a;
  }
  __syncthreads();
  // softmax per row: 8 rows x 32 lanes
  {
    int nl = t >> 5, l = t & 31;
    float* row = sc + nl * 1025;
    float mx = -1e30f;
    for (int m = l; m < 1024; m += 32) mx = fmaxf(mx, row[m]);
#pragma unroll
    for (int o = 16; o > 0; o >>= 1) mx = fmaxf(mx, __shfl_xor(mx, o, 64));
    float ssum = 0.0f;
    for (int m = l; m < 1024; m += 32) {
      float e = __expf(row[m] - mx);
      row[m] = e;
      ssum += e;
    }
#pragma unroll
    for (int o = 16; o > 0; o >>= 1) ssum += __shfl_xor(ssum, o, 64);
    if (l == 0) inv_s[nl] = 1.0f / ssum;
  }
  __syncthreads();
  // PV: thread owns co = t&127, nl = (t>>7) + 2j. v staged 32-m tiles in LDS.
  const int co = t & 127, nb = t >> 7;
  float acc[4] = {0.f, 0.f, 0.f, 0.f};
  for (int mt = 0; mt < 1024; mt += 32) {
#pragma unroll
    for (int i = 0; i < 16; i++) {
      int idx = (i << 8) + t;
      int c2 = idx >> 5, m2 = idx & 31;
      vt[c2 * 33 + m2] = vb[(c2 << 10) + mt + m2];
    }
    __syncthreads();
#pragma unroll 4
    for (int m = 0; m < 32; m++) {
      float vv = vt[co * 33 + m];
      acc[0] += vv * sc[nb * 1025 + mt + m];
      acc[1] += vv * sc[(nb + 2) * 1025 + mt + m];
      acc[2] += vv * sc[(nb + 4) * 1025 + mt + m];
      acc[3] += vv * sc[(nb + 6) * 1025 + mt + m];
    }
    __syncthreads();
  }
  float g = gamma[sidx[b]];
#pragma unroll
  for (int j = 0; j < 4; j++) {
    int nl = nb + 2 * j;
    int n = n0 + nl;
    y[(((size_t)b * 128 + co) << 10) + n] = g * acc[j] * inv_s[nl] + xb[(co << 10) + n];
  }
}

// ---------------------------------------------------------------------------
// conv2: y (B,128,32,32) -> x2 raw (B,256,16,16), k4 s2 p1, +bias
// grid (B, 32): block handles 8 co; thread: 4 pixels x 2 co (cg = t>>6).
// LDS: 8 input slabs with zero halo (34x34), weights 8co x 8ci x 16.
__global__ __launch_bounds__(256) void k_conv2(
    const float* __restrict__ y, const float* __restrict__ w2,
    const float* __restrict__ b2, const int* __restrict__ sidx,
    float* __restrict__ x2) {
  __shared__ float ysh[8 * 1156];  // 34*34 = 1156 per ci slab
  __shared__ float wsh[1024];      // [cw][128]
  const int t = threadIdx.x;
  const int b = blockIdx.x, co0 = blockIdx.y * 8;
  const int s = sidx[b];
  const int cg = t >> 6;  // co pair: co0 + cg*2 + {0,1}
  const int pq = t & 63;  // pixels pq + 64j
  for (int i = t; i < 8 * 1156; i += 256) ysh[i] = 0.0f;
  float acc[4][2];
#pragma unroll
  for (int c = 0; c < 2; c++) {
    float bb = b2[s * 256 + co0 + cg * 2 + c];
#pragma unroll
    for (int j = 0; j < 4; j++) acc[j][c] = bb;
  }
  const float* yb = y + (size_t)b * 128 * 1024;
  const float* wbp = w2 + ((size_t)(s * 256 + co0)) * 2048;
  __syncthreads();
  for (int cc = 0; cc < 16; cc++) {  // 8 ci per chunk
#pragma unroll
    for (int i = 0; i < 32; i++) {
      int idx = (i << 8) + t;
      int ci = idx >> 10, p = idx & 1023;
      int ih = p >> 5, iw = p & 31;
      ysh[ci * 1156 + (ih + 1) * 34 + (iw + 1)] = yb[((cc * 8 + ci) << 10) + p];
    }
#pragma unroll
    for (int i = 0; i < 4; i++) {
      int idx = (i << 8) + t;
      wsh[idx] = wbp[(idx >> 7) * 2048 + cc * 128 + (idx & 127)];
    }
    __syncthreads();
#pragma unroll
    for (int ci = 0; ci < 8; ci++) {
      float wr[32];  // 2co x 16 taps
#pragma unroll
      for (int u = 0; u < 32; u++)
        wr[u] = wsh[(cg * 2 + (u >> 4)) * 128 + ci * 16 + (u & 15)];
#pragma unroll
      for (int j = 0; j < 4; j++) {
        int pix = pq + (j << 6);
        int oh = pix >> 4, ow = pix & 15;
        const float* yp = ysh + ci * 1156 + (oh * 2) * 34 + ow * 2;
        float yv[16];
#pragma unroll
        for (int kh = 0; kh < 4; kh++)
#pragma unroll
          for (int kw = 0; kw < 4; kw++) yv[kh * 4 + kw] = yp[kh * 34 + kw];
#pragma unroll
        for (int c = 0; c < 2; c++)
#pragma unroll
          for (int u = 0; u < 16; u++) acc[j][c] += wr[c * 16 + u] * yv[u];
      }
    }
    __syncthreads();
  }
#pragma unroll
  for (int c = 0; c < 2; c++)
#pragma unroll
    for (int j = 0; j < 4; j++)
      x2[(((size_t)b * 256 + co0 + cg * 2 + c) << 8) + pq + (j << 6)] = acc[j][c];
}

// ---------------------------------------------------------------------------
// head: x2 (B,256,16,16) -> out (B,1,15,15), k4 s1 p1, +bias
__global__ __launch_bounds__(256) void k_head(
    const float* __restrict__ x2, const float* __restrict__ wh,
    const float* __restrict__ bh, const int* __restrict__ sidx,
    float* __restrict__ out) {
  int bp = blockIdx.x;
  int b = bp / 225, pix = bp % 225;
  int oh = pix / 15, ow = pix % 15;
  int s = sidx[b];
  int ci = threadIdx.x;
  const float* xp = x2 + (((size_t)b * 256 + ci) << 8);
  const float* wp = wh + s * 4096 + ci * 16;
  float acc = 0.0f;
#pragma unroll
  for (int kh = 0; kh < 4; kh++) {
    int ih = oh - 1 + kh;
    if ((unsigned)ih >= 16u) continue;
#pragma unroll
    for (int kw = 0; kw < 4; kw++) {
      int iw = ow - 1 + kw;
      if ((unsigned)iw >= 16u) continue;
      acc += wp[kh * 4 + kw] * xp[(ih << 4) + iw];
    }
  }
#pragma unroll
  for (int o = 32; o > 0; o >>= 1) acc += __shfl_down(acc, o, 64);
  __shared__ float red[4];
  if ((threadIdx.x & 63) == 0) red[threadIdx.x >> 6] = acc;
  __syncthreads();
  if (threadIdx.x == 0) {
    float r = red[0] + red[1] + red[2] + red[3] + bh[s];
    out[b * 225 + pix] = r;
  }
}

// ---------------------------------------------------------------------------
extern "C" void kernel_launch(void* const* d_in, const int* in_sizes, int n_in,
                              void* d_out, int out_size, void* d_ws, size_t ws_size,
                              hipStream_t stream) {
  const float* img = (const float*)d_in[0];
  const int* sidx = (const int*)d_in[1];
  const float* w0 = (const float*)d_in[2];
  const float* b0 = (const float*)d_in[3];
  const float* w1 = (const float*)d_in[4];
  const float* b1 = (const float*)d_in[5];
  const float* w2 = (const float*)d_in[6];
  const float* b2 = (const float*)d_in[7];
  const float* wq = (const float*)d_in[8];
  const float* bq = (const float*)d_in[9];
  const float* wk = (const float*)d_in[10];
  const float* bk = (const float*)d_in[11];
  const float* wv = (const float*)d_in[12];
  const float* bv = (const float*)d_in[13];
  const float* gamma = (const float*)d_in[14];
  const float* wh = (const float*)d_in[15];
  const float* bh = (const float*)d_in[16];
  float* out = (float*)d_out;

  float* ws = (float*)d_ws;
  float* x0 = ws + 0;        // (B,64,64,64)
  float* x1 = ws + 4194304;  // (B,128,32,32)
  float* q = ws + 6291456;   // (B,16,1024)
  float* k = ws + 6553600;
  float* v = ws + 6815744;   // (B,128,1024)
  float* x2 = ws + 8912896;  // (B,256,16,16)
  float* y = x0;             // alias, x0 dead after conv1

  const int B = 16;

  k_conv0<<<dim3(B * 64, 16), 256, 0, stream>>>(img, w0, b0, sidx, x0);
  k_conv1<<<dim3(B, 32), 256, 0, stream>>>(x0, w1, b1, sidx, x1);
  k_inorm<1024><<<B * 128, 256, 0, stream>>>(x1);
  k_conv1x1<<<B * 16, 256, 0, stream>>>(x1, wq, bq, sidx, q, 16);
  k_conv1x1<<<B * 16, 256, 0, stream>>>(x1, wk, bk, sidx, k, 16);
  k_conv1x1<<<B * 128, 256, 0, stream>>>(x1, wv, bv, sidx, v, 128);
  k_attn<<<B * 128, 256, 0, stream>>>(q, k, v, x1, gamma, sidx, y);
  k_conv2<<<dim3(B, 32), 256, 0, stream>>>(y, w2, b2, sidx, x2);
  k_inorm<256><<<B * 256, 256, 0, stream>>>(x2);
  k_head<<<B * 225, 256, 0, stream>>>(x2, wh, bh, sidx, out);
}

// Round 4
// 599.568 us; speedup vs baseline: 4.5151x; 1.2909x over previous
//
#include <hip/hip_runtime.h>

#define LRELU(x) ((x) > 0.0f ? (x) : 0.2f * (x))

// ---------------------------------------------------------------------------
// conv0: img (B,1,128,128) -> x0 (B,64,64,64), k4 s2 p1, +bias, +leaky
__global__ __launch_bounds__(256) void k_conv0(
    const float* __restrict__ img, const float* __restrict__ w0,
    const float* __restrict__ b0, const int* __restrict__ sidx,
    float* __restrict__ x0) {
  int bc = blockIdx.x;
  int b = bc >> 6, co = bc & 63;
  int pix = blockIdx.y * 256 + threadIdx.x;
  int oh = pix >> 6, ow = pix & 63;
  int s = sidx[b];
  const float* w = w0 + (s * 64 + co) * 16;
  float wr[16];
#pragma unroll
  for (int i = 0; i < 16; i++) wr[i] = w[i];
  float acc = b0[s * 64 + co];
  const float* ip = img + (size_t)b * 128 * 128;
  int ih0 = oh * 2 - 1, iw0 = ow * 2 - 1;
#pragma unroll
  for (int kh = 0; kh < 4; kh++) {
    int ih = ih0 + kh;
    if ((unsigned)ih >= 128u) continue;
#pragma unroll
    for (int kw = 0; kw < 4; kw++) {
      int iw = iw0 + kw;
      if ((unsigned)iw >= 128u) continue;
      acc += wr[kh * 4 + kw] * ip[ih * 128 + iw];
    }
  }
  x0[(((size_t)b * 64 + co) << 12) + pix] = LRELU(acc);
}

// ---------------------------------------------------------------------------
// conv1: x0 (B,64,64,64) -> x1 raw (B,128,32,32), k4 s2 p1, +bias
__global__ __launch_bounds__(256) void k_conv1(
    const float* __restrict__ x0, const float* __restrict__ w1,
    const float* __restrict__ b1, const int* __restrict__ sidx,
    float* __restrict__ x1) {
  __shared__ float ysh[2 * 4356];
  __shared__ float wsh[128];
  const int t = threadIdx.x;
  const int b = blockIdx.x, co0 = blockIdx.y * 4;
  const int s = sidx[b];
  for (int i = t; i < 2 * 4356; i += 256) ysh[i] = 0.0f;
  float acc[4][4];
#pragma unroll
  for (int c = 0; c < 4; c++) {
    float bb = b1[s * 128 + co0 + c];
#pragma unroll
    for (int j = 0; j < 4; j++) acc[j][c] = bb;
  }
  const float* xb = x0 + (size_t)b * 64 * 4096;
  const float* wb = w1 + ((size_t)(s * 128 + co0)) * 1024;
  __syncthreads();
  for (int cc = 0; cc < 32; cc++) {
#pragma unroll
    for (int i = 0; i < 32; i++) {
      int idx = (i << 8) + t;
      int ci = idx >> 12, p = idx & 4095;
      int ih = p >> 6, iw = p & 63;
      ysh[ci * 4356 + (ih + 1) * 66 + (iw + 1)] = xb[((cc * 2 + ci) << 12) + p];
    }
    if (t < 128) wsh[t] = wb[(t >> 5) * 1024 + cc * 32 + (t & 31)];
    __syncthreads();
#pragma unroll
    for (int ci = 0; ci < 2; ci++) {
      float wr[64];
#pragma unroll
      for (int u = 0; u < 64; u++) wr[u] = wsh[(u >> 4) * 32 + ci * 16 + (u & 15)];
#pragma unroll
      for (int j = 0; j < 4; j++) {
        int pix = t + (j << 8);
        int oh = pix >> 5, ow = pix & 31;
        const float* yp = ysh + ci * 4356 + (oh * 2) * 66 + ow * 2;
        float yv[16];
#pragma unroll
        for (int kh = 0; kh < 4; kh++)
#pragma unroll
          for (int kw = 0; kw < 4; kw++) yv[kh * 4 + kw] = yp[kh * 66 + kw];
#pragma unroll
        for (int c = 0; c < 4; c++)
#pragma unroll
          for (int u = 0; u < 16; u++) acc[j][c] += wr[c * 16 + u] * yv[u];
      }
    }
    __syncthreads();
  }
#pragma unroll
  for (int c = 0; c < 4; c++)
#pragma unroll
    for (int j = 0; j < 4; j++)
      x1[(((size_t)b * 128 + co0 + c) << 10) + t + (j << 8)] = acc[j][c];
}

// ---------------------------------------------------------------------------
// instance norm (+leaky) in place
template <int NPIX>
__global__ __launch_bounds__(256) void k_inorm(float* __restrict__ x) {
  float* p = x + (size_t)blockIdx.x * NPIX;
  float sum = 0.0f, sq = 0.0f;
  for (int i = threadIdx.x; i < NPIX; i += 256) {
    float v = p[i];
    sum += v;
    sq += v * v;
  }
#pragma unroll
  for (int o = 32; o > 0; o >>= 1) {
    sum += __shfl_down(sum, o, 64);
    sq += __shfl_down(sq, o, 64);
  }
  __shared__ float red[8];
  int wid = threadIdx.x >> 6;
  if ((threadIdx.x & 63) == 0) {
    red[wid] = sum;
    red[4 + wid] = sq;
  }
  __syncthreads();
  if (threadIdx.x == 0) {
    red[0] = red[0] + red[1] + red[2] + red[3];
    red[4] = red[4] + red[5] + red[6] + red[7];
  }
  __syncthreads();
  float m = red[0] * (1.0f / NPIX);
  float var = red[4] * (1.0f / NPIX) - m * m;
  float inv = rsqrtf(var + 1e-5f);
  for (int i = threadIdx.x; i < NPIX; i += 256) {
    float v = (p[i] - m) * inv;
    p[i] = LRELU(v);
  }
}

// ---------------------------------------------------------------------------
// 1x1 conv, register-tiled GEMM: out (B,CO,1024) = w(S,CO,128) @ x(B,128,1024)
// grid (B, (CO/16)*4); block tile 16co x 256n; thread 4co x 4n; K chunks of 32.
__global__ __launch_bounds__(256) void k_conv1x1(
    const float* __restrict__ xin, const float* __restrict__ w,
    const float* __restrict__ bias, const int* __restrict__ sidx,
    float* __restrict__ out, int CO) {
  __shared__ float xsh[32 * 256];
  __shared__ float wsh[16 * 32];
  const int t = threadIdx.x;
  const int b = blockIdx.x;
  const int cow = blockIdx.y >> 2, nw = blockIdx.y & 3;
  const int co0 = cow * 16, nn0 = nw * 256;
  const int s = sidx[b];
  const int cg = t >> 6, ng = t & 63;  // co = co0+cg*4+c, n = nn0+ng*4+j
  const float* xb = xin + (size_t)b * 128 * 1024;
  float4 acc4[4];
#pragma unroll
  for (int c = 0; c < 4; c++) {
    float bb = bias[s * CO + co0 + cg * 4 + c];
    acc4[c] = make_float4(bb, bb, bb, bb);
  }
  for (int cc = 0; cc < 4; cc++) {
#pragma unroll
    for (int k = 0; k < 8; k++) {
      int id = t + (k << 8);
      int ci = id >> 6, nf = id & 63;
      ((float4*)xsh)[id] = ((const float4*)(xb + (cc * 32 + ci) * 1024 + nn0))[nf];
    }
    if (t < 128)
      ((float4*)wsh)[t] =
          ((const float4*)(w + ((size_t)(s * CO + co0 + (t >> 3))) * 128 + cc * 32))[t & 7];
    __syncthreads();
#pragma unroll
    for (int ci4 = 0; ci4 < 8; ci4++) {
      float4 wv[4], xv[4];
#pragma unroll
      for (int c = 0; c < 4; c++) wv[c] = ((const float4*)wsh)[(cg * 4 + c) * 8 + ci4];
#pragma unroll
      for (int i = 0; i < 4; i++) xv[i] = ((const float4*)xsh)[(ci4 * 4 + i) * 64 + ng];
#pragma unroll
      for (int c = 0; c < 4; c++)
#pragma unroll
        for (int i = 0; i < 4; i++) {
          float wvc = i == 0 ? wv[c].x : i == 1 ? wv[c].y : i == 2 ? wv[c].z : wv[c].w;
          acc4[c].x += wvc * xv[i].x;
          acc4[c].y += wvc * xv[i].y;
          acc4[c].z += wvc * xv[i].z;
          acc4[c].w += wvc * xv[i].w;
        }
    }
    __syncthreads();
  }
#pragma unroll
  for (int c = 0; c < 4; c++) {
    int co = co0 + cg * 4 + c;
    ((float4*)(out + ((size_t)b * CO + co) * 1024 + nn0))[ng] = acc4[c];
  }
}

// ---------------------------------------------------------------------------
// fused self-attention per (b, 8-n tile). Skewed-transposed scores sc[m][nl],
// register-tiled PV (8co x 8nl per thread, m split 16-way) + LDS reduction.
// grid (B*128), block 256.
__device__ __forceinline__ int scidx(int m, int nl) { return m * 8 + (m & ~3) + nl; }

__global__ __launch_bounds__(256) void k_attn(
    const float* __restrict__ q, const float* __restrict__ k, const float* __restrict__ v,
    const float* __restrict__ x1, const float* __restrict__ gamma,
    const int* __restrict__ sidx, float* __restrict__ y) {
  __shared__ float sc[9216];  // skewed [1024 m][8 nl] : m*8 + (m&~3) + nl
  __shared__ float vt[8192];  // [128 co][64 m] chunk
  __shared__ float ql[128];   // [16 c][8 nl]
  __shared__ float inv_s[8];
  const int t = threadIdx.x;
  const int b = blockIdx.x >> 7;
  const int n0 = (blockIdx.x & 127) << 3;
  const float* qb = q + (size_t)b * 16 * 1024;
  const float* kb = k + (size_t)b * 16 * 1024;
  const float* vb = v + (size_t)b * 128 * 1024;
  const float* xb = x1 + (size_t)b * 128 * 1024;
  if (t < 128) {
    int c = t >> 3, nl = t & 7;
    ql[c * 8 + nl] = qb[(c << 10) + n0 + nl];
  }
  __syncthreads();
  // ---- scores: thread computes m = 4t..4t+3, all 8 nl
  {
    float acc[4][8];
#pragma unroll
    for (int j = 0; j < 4; j++)
#pragma unroll
      for (int nl = 0; nl < 8; nl++) acc[j][nl] = 0.0f;
#pragma unroll
    for (int c = 0; c < 16; c++) {
      float4 kv = ((const float4*)(kb + (c << 10)))[t];
      float4 qa = ((const float4*)ql)[c * 2];
      float4 qbv = ((const float4*)ql)[c * 2 + 1];
#pragma unroll
      for (int j = 0; j < 4; j++) {
        float kk = j == 0 ? kv.x : j == 1 ? kv.y : j == 2 ? kv.z : kv.w;
        acc[j][0] += kk * qa.x;
        acc[j][1] += kk * qa.y;
        acc[j][2] += kk * qa.z;
        acc[j][3] += kk * qa.w;
        acc[j][4] += kk * qbv.x;
        acc[j][5] += kk * qbv.y;
        acc[j][6] += kk * qbv.z;
        acc[j][7] += kk * qbv.w;
      }
    }
#pragma unroll
    for (int j = 0; j < 4; j++) {
      int m = t * 4 + j;
      int base = scidx(m, 0) >> 2;
      ((float4*)sc)[base] = make_float4(acc[j][0], acc[j][1], acc[j][2], acc[j][3]);
      ((float4*)sc)[base + 1] = make_float4(acc[j][4], acc[j][5], acc[j][6], acc[j][7]);
    }
  }
  __syncthreads();
  // ---- softmax per nl row: 8 rows x 32 lanes
  {
    int nl = t >> 5, l = t & 31;
    float mx = -1e30f;
    for (int m = l; m < 1024; m += 32) mx = fmaxf(mx, sc[scidx(m, nl)]);
#pragma unroll
    for (int o = 16; o > 0; o >>= 1) mx = fmaxf(mx, __shfl_xor(mx, o, 64));
    float ssum = 0.0f;
    for (int m = l; m < 1024; m += 32) {
      float e = __expf(sc[scidx(m, nl)] - mx);
      sc[scidx(m, nl)] = e;
      ssum += e;
    }
#pragma unroll
    for (int o = 16; o > 0; o >>= 1) ssum += __shfl_xor(ssum, o, 64);
    if (l == 0) inv_s[nl] = 1.0f / ssum;
  }
  __syncthreads();
  // ---- PV: thread (cog=t>>4, mg=t&15): 8co x 8nl over m = {64k + mg*4 + j}
  const int cog = t >> 4, mg = t & 15;
  float4 acc4[16];  // [c][nl0..3],[c][nl4..7]
#pragma unroll
  for (int i = 0; i < 16; i++) acc4[i] = make_float4(0.f, 0.f, 0.f, 0.f);
  for (int mt = 0; mt < 1024; mt += 64) {
    // stage vt[128][64]
#pragma unroll
    for (int kk = 0; kk < 8; kk++) {
      int id = t + (kk << 8);
      int c2 = id >> 4, m4 = id & 15;
      ((float4*)vt)[id] = ((const float4*)(vb + (c2 << 10) + mt))[m4];
    }
    __syncthreads();
    float4 vt4[8];
#pragma unroll
    for (int c = 0; c < 8; c++) vt4[c] = ((const float4*)vt)[(cog * 8 + c) * 16 + mg];
#pragma unroll
    for (int j = 0; j < 4; j++) {
      int m = mt + mg * 4 + j;
      int base = scidx(m, 0) >> 2;
      float4 s0 = ((const float4*)sc)[base];
      float4 s1 = ((const float4*)sc)[base + 1];
#pragma unroll
      for (int c = 0; c < 8; c++) {
        float vv = j == 0 ? vt4[c].x : j == 1 ? vt4[c].y : j == 2 ? vt4[c].z : vt4[c].w;
        acc4[c * 2].x += vv * s0.x;
        acc4[c * 2].y += vv * s0.y;
        acc4[c * 2].z += vv * s0.z;
        acc4[c * 2].w += vv * s0.w;
        acc4[c * 2 + 1].x += vv * s1.x;
        acc4[c * 2 + 1].y += vv * s1.y;
        acc4[c * 2 + 1].z += vv * s1.z;
        acc4[c * 2 + 1].w += vv * s1.w;
      }
    }
    __syncthreads();
  }
  // ---- reduce partials across 16 mg (tree via LDS, reuse sc)
  for (int h = 8; h >= 1; h >>= 1) {
    if (mg >= h && mg < 2 * h) {
      int base = ((mg - h) * 16 + cog) * 16;
#pragma unroll
      for (int kk = 0; kk < 16; kk++) ((float4*)sc)[base + kk] = acc4[kk];
    }
    __syncthreads();
    if (mg < h) {
      int base = (mg * 16 + cog) * 16;
#pragma unroll
      for (int kk = 0; kk < 16; kk++) {
        float4 o = ((const float4*)sc)[base + kk];
        acc4[kk].x += o.x;
        acc4[kk].y += o.y;
        acc4[kk].z += o.z;
        acc4[kk].w += o.w;
      }
    }
    __syncthreads();
  }
  // ---- redistribute: mg0 threads hold finals for co = cog*8..+7
  if (mg == 0) {
#pragma unroll
    for (int kk = 0; kk < 16; kk++) ((float4*)sc)[cog * 16 + kk] = acc4[kk];
  }
  __syncthreads();
  {
    float g = gamma[sidx[b]];
    float4 val = ((const float4*)sc)[t];  // ids t*4..t*4+3
#pragma unroll
    for (int ii = 0; ii < 4; ii++) {
      int id = t * 4 + ii;
      int co = id >> 3, nl = id & 7;
      float vv = ii == 0 ? val.x : ii == 1 ? val.y : ii == 2 ? val.z : val.w;
      int n = n0 + nl;
      y[(((size_t)b * 128 + co) << 10) + n] = g * vv * inv_s[nl] + xb[(co << 10) + n];
    }
  }
}

// ---------------------------------------------------------------------------
// conv2: y (B,128,32,32) -> x2 raw (B,256,16,16), k4 s2 p1, +bias
__global__ __launch_bounds__(256) void k_conv2(
    const float* __restrict__ y, const float* __restrict__ w2,
    const float* __restrict__ b2, const int* __restrict__ sidx,
    float* __restrict__ x2) {
  __shared__ float ysh[8 * 1156];
  __shared__ float wsh[1024];
  const int t = threadIdx.x;
  const int b = blockIdx.x, co0 = blockIdx.y * 8;
  const int s = sidx[b];
  const int cg = t >> 6;
  const int pq = t & 63;
  for (int i = t; i < 8 * 1156; i += 256) ysh[i] = 0.0f;
  float acc[4][2];
#pragma unroll
  for (int c = 0; c < 2; c++) {
    float bb = b2[s * 256 + co0 + cg * 2 + c];
#pragma unroll
    for (int j = 0; j < 4; j++) acc[j][c] = bb;
  }
  const float* yb = y + (size_t)b * 128 * 1024;
  const float* wbp = w2 + ((size_t)(s * 256 + co0)) * 2048;
  __syncthreads();
  for (int cc = 0; cc < 16; cc++) {
#pragma unroll
    for (int i = 0; i < 32; i++) {
      int idx = (i << 8) + t;
      int ci = idx >> 10, p = idx & 1023;
      int ih = p >> 5, iw = p & 31;
      ysh[ci * 1156 + (ih + 1) * 34 + (iw + 1)] = yb[((cc * 8 + ci) << 10) + p];
    }
#pragma unroll
    for (int i = 0; i < 4; i++) {
      int idx = (i << 8) + t;
      wsh[idx] = wbp[(idx >> 7) * 2048 + cc * 128 + (idx & 127)];
    }
    __syncthreads();
#pragma unroll
    for (int ci = 0; ci < 8; ci++) {
      float wr[32];
#pragma unroll
      for (int u = 0; u < 32; u++)
        wr[u] = wsh[(cg * 2 + (u >> 4)) * 128 + ci * 16 + (u & 15)];
#pragma unroll
      for (int j = 0; j < 4; j++) {
        int pix = pq + (j << 6);
        int oh = pix >> 4, ow = pix & 15;
        const float* yp = ysh + ci * 1156 + (oh * 2) * 34 + ow * 2;
        float yv[16];
#pragma unroll
        for (int kh = 0; kh < 4; kh++)
#pragma unroll
          for (int kw = 0; kw < 4; kw++) yv[kh * 4 + kw] = yp[kh * 34 + kw];
#pragma unroll
        for (int c = 0; c < 2; c++)
#pragma unroll
          for (int u = 0; u < 16; u++) acc[j][c] += wr[c * 16 + u] * yv[u];
      }
    }
    __syncthreads();
  }
#pragma unroll
  for (int c = 0; c < 2; c++)
#pragma unroll
    for (int j = 0; j < 4; j++)
      x2[(((size_t)b * 256 + co0 + cg * 2 + c) << 8) + pq + (j << 6)] = acc[j][c];
}

// ---------------------------------------------------------------------------
// head: x2 (B,256,16,16) -> out (B,1,15,15), k4 s1 p1, +bias
__global__ __launch_bounds__(256) void k_head(
    const float* __restrict__ x2, const float* __restrict__ wh,
    const float* __restrict__ bh, const int* __restrict__ sidx,
    float* __restrict__ out) {
  int bp = blockIdx.x;
  int b = bp / 225, pix = bp % 225;
  int oh = pix / 15, ow = pix % 15;
  int s = sidx[b];
  int ci = threadIdx.x;
  const float* xp = x2 + (((size_t)b * 256 + ci) << 8);
  const float* wp = wh + s * 4096 + ci * 16;
  float acc = 0.0f;
#pragma unroll
  for (int kh = 0; kh < 4; kh++) {
    int ih = oh - 1 + kh;
    if ((unsigned)ih >= 16u) continue;
#pragma unroll
    for (int kw = 0; kw < 4; kw++) {
      int iw = ow - 1 + kw;
      if ((unsigned)iw >= 16u) continue;
      acc += wp[kh * 4 + kw] * xp[(ih << 4) + iw];
    }
  }
#pragma unroll
  for (int o = 32; o > 0; o >>= 1) acc += __shfl_down(acc, o, 64);
  __shared__ float red[4];
  if ((threadIdx.x & 63) == 0) red[threadIdx.x >> 6] = acc;
  __syncthreads();
  if (threadIdx.x == 0) {
    float r = red[0] + red[1] + red[2] + red[3] + bh[s];
    out[b * 225 + pix] = r;
  }
}

// ---------------------------------------------------------------------------
extern "C" void kernel_launch(void* const* d_in, const int* in_sizes, int n_in,
                              void* d_out, int out_size, void* d_ws, size_t ws_size,
                              hipStream_t stream) {
  const float* img = (const float*)d_in[0];
  const int* sidx = (const int*)d_in[1];
  const float* w0 = (const float*)d_in[2];
  const float* b0 = (const float*)d_in[3];
  const float* w1 = (const float*)d_in[4];
  const float* b1 = (const float*)d_in[5];
  const float* w2 = (const float*)d_in[6];
  const float* b2 = (const float*)d_in[7];
  const float* wq = (const float*)d_in[8];
  const float* bq = (const float*)d_in[9];
  const float* wk = (const float*)d_in[10];
  const float* bk = (const float*)d_in[11];
  const float* wv = (const float*)d_in[12];
  const float* bv = (const float*)d_in[13];
  const float* gamma = (const float*)d_in[14];
  const float* wh = (const float*)d_in[15];
  const float* bh = (const float*)d_in[16];
  float* out = (float*)d_out;

  float* ws = (float*)d_ws;
  float* x0 = ws + 0;        // (B,64,64,64)
  float* x1 = ws + 4194304;  // (B,128,32,32)
  float* q = ws + 6291456;   // (B,16,1024)
  float* k = ws + 6553600;
  float* v = ws + 6815744;   // (B,128,1024)
  float* x2 = ws + 8912896;  // (B,256,16,16)
  float* y = x0;             // alias, x0 dead after conv1

  const int B = 16;

  k_conv0<<<dim3(B * 64, 16), 256, 0, stream>>>(img, w0, b0, sidx, x0);
  k_conv1<<<dim3(B, 32), 256, 0, stream>>>(x0, w1, b1, sidx, x1);
  k_inorm<1024><<<B * 128, 256, 0, stream>>>(x1);
  k_conv1x1<<<dim3(B, 4), 256, 0, stream>>>(x1, wq, bq, sidx, q, 16);
  k_conv1x1<<<dim3(B, 4), 256, 0, stream>>>(x1, wk, bk, sidx, k, 16);
  k_conv1x1<<<dim3(B, 32), 256, 0, stream>>>(x1, wv, bv, sidx, v, 128);
  k_attn<<<B * 128, 256, 0, stream>>>(q, k, v, x1, gamma, sidx, y);
  k_conv2<<<dim3(B, 32), 256, 0, stream>>>(y, w2, b2, sidx, x2);
  k_inorm<256><<<B * 256, 256, 0, stream>>>(x2);
  k_head<<<B * 225, 256, 0, stream>>>(x2, wh, bh, sidx, out);
}

// Round 5
// 482.637 us; speedup vs baseline: 5.6090x; 1.2423x over previous
//
#include <hip/hip_runtime.h>

#define LRELU(x) ((x) > 0.0f ? (x) : 0.2f * (x))

typedef short bf16x8 __attribute__((ext_vector_type(8)));
typedef float f32x4 __attribute__((ext_vector_type(4)));

__device__ __forceinline__ short f2bf(float f) {
  union { float f; unsigned u; } x{f};
  return (short)((x.u + 0x7FFF + ((x.u >> 16) & 1)) >> 16);
}

// ---------------------------------------------------------------------------
// conv0: img (B,1,128,128) -> x0 (B,64,64,64), k4 s2 p1, +bias, +leaky
__global__ __launch_bounds__(256) void k_conv0(
    const float* __restrict__ img, const float* __restrict__ w0,
    const float* __restrict__ b0, const int* __restrict__ sidx,
    float* __restrict__ x0) {
  int bc = blockIdx.x;
  int b = bc >> 6, co = bc & 63;
  int pix = blockIdx.y * 256 + threadIdx.x;
  int oh = pix >> 6, ow = pix & 63;
  int s = sidx[b];
  const float* w = w0 + (s * 64 + co) * 16;
  float wr[16];
#pragma unroll
  for (int i = 0; i < 16; i++) wr[i] = w[i];
  float acc = b0[s * 64 + co];
  const float* ip = img + (size_t)b * 128 * 128;
  int ih0 = oh * 2 - 1, iw0 = ow * 2 - 1;
#pragma unroll
  for (int kh = 0; kh < 4; kh++) {
    int ih = ih0 + kh;
    if ((unsigned)ih >= 128u) continue;
#pragma unroll
    for (int kw = 0; kw < 4; kw++) {
      int iw = iw0 + kw;
      if ((unsigned)iw >= 128u) continue;
      acc += wr[kh * 4 + kw] * ip[ih * 128 + iw];
    }
  }
  x0[(((size_t)b * 64 + co) << 12) + pix] = LRELU(acc);
}

// ---------------------------------------------------------------------------
// MFMA implicit-GEMM k4s2p1 conv (NO bias - cancelled by following inorm).
// GEMM per batch: C[co][n] = sum_k W[co][k] * B[k][n], k=(ci,kh,kw), n=(oh,ow).
// Block: 256 thr = 4 waves (2x2), block tile 64co x 64n, K-chunks of 32 (2 ci).
// LDS: A[64 co][k-contig, stride 40 bf16], B[64 n][k-contig, stride 40 bf16];
// both fragment loads are single ds_read_b128, stride 80B = 20 banks (no confl).
template <int CI, int CO, int HIN, int OWSHIFT>
__global__ __launch_bounds__(256) void k_conv_mfma(
    const float* __restrict__ xin, const float* __restrict__ wgt,
    const int* __restrict__ sidx, float* __restrict__ xout) {
  constexpr int WIN = HIN;
  constexpr int OW = 1 << OWSHIFT;
  constexpr int OH = HIN / 2;
  constexpr int NPB = OH * OW;  // pixels per batch
  constexpr int NT = NPB / 64;  // n-tiles
  constexpr int KCH = CI / 2;   // 32-k chunks
  __shared__ __align__(16) short Ash[64 * 40];
  __shared__ __align__(16) short Bsh[64 * 40];
  const int t = threadIdx.x;
  const int b = blockIdx.x;
  const int co0 = (blockIdx.y / NT) * 64;
  const int n0 = (blockIdx.y % NT) * 64;
  const int s = sidx[b];
  const int lane = t & 63, wv = t >> 6;
  const int wm = (wv >> 1) * 32, wn = (wv & 1) * 32;
  const int quad = lane >> 4, l16 = lane & 15;

  // A staging: thread -> (co row = t&63, 8-k group = t>>6)
  const int arow = t & 63, ag = t >> 6;
  const float* wrow = wgt + ((size_t)(s * CO + co0 + arow)) * (CI * 16) + ag * 8;
  // B staging: thread -> (n = t&63, 8-k group = t>>6); 8 k = 2 kh rows x 4 kw
  const int bn = t & 63, bg = t >> 6;
  const int p = n0 + bn;
  const int oh = p >> OWSHIFT, ow = p & (OW - 1);
  const int iw0 = 2 * ow - 1;
  const int ihb = 2 * oh - 1 + (bg & 1) * 2;
  const float* xb = xin + ((size_t)b * CI + (bg >> 1)) * (HIN * WIN);

  f32x4 acc[2][2];
#pragma unroll
  for (int i = 0; i < 2; i++)
#pragma unroll
    for (int j = 0; j < 2; j++) acc[i][j] = (f32x4){0.f, 0.f, 0.f, 0.f};

  for (int kc = 0; kc < KCH; kc++) {
    {  // stage A chunk: w[s][co][kc*32 + ag*8 .. +7], contiguous fp32
      const float* wp = wrow + kc * 32;
      float4 f0 = *(const float4*)wp;
      float4 f1 = *(const float4*)(wp + 4);
      bf16x8 av;
      av[0] = f2bf(f0.x); av[1] = f2bf(f0.y); av[2] = f2bf(f0.z); av[3] = f2bf(f0.w);
      av[4] = f2bf(f1.x); av[5] = f2bf(f1.y); av[6] = f2bf(f1.z); av[7] = f2bf(f1.w);
      *(bf16x8*)&Ash[arow * 40 + ag * 8] = av;
    }
    {  // stage B chunk: im2col gather, ci = kc*2 + (bg>>1)
      const float* yp = xb + (size_t)kc * 2 * (HIN * WIN);
      bf16x8 bv;
#pragma unroll
      for (int r = 0; r < 2; r++) {
        int ih = ihb + r;
        bool rok = (unsigned)ih < (unsigned)HIN;
        const float* rp = yp + ih * WIN;
#pragma unroll
        for (int kwi = 0; kwi < 4; kwi++) {
          int iw = iw0 + kwi;
          float f = (rok && (unsigned)iw < (unsigned)WIN) ? rp[iw] : 0.0f;
          bv[r * 4 + kwi] = f2bf(f);
        }
      }
      *(bf16x8*)&Bsh[bn * 40 + bg * 8] = bv;
    }
    __syncthreads();
    bf16x8 af[2], bfv[2];
#pragma unroll
    for (int i = 0; i < 2; i++)
      af[i] = *(const bf16x8*)&Ash[(wm + i * 16 + l16) * 40 + quad * 8];
#pragma unroll
    for (int j = 0; j < 2; j++)
      bfv[j] = *(const bf16x8*)&Bsh[(wn + j * 16 + l16) * 40 + quad * 8];
#pragma unroll
    for (int i = 0; i < 2; i++)
#pragma unroll
      for (int j = 0; j < 2; j++)
        acc[i][j] = __builtin_amdgcn_mfma_f32_16x16x32_bf16(af[i], bfv[j], acc[i][j], 0, 0, 0);
    __syncthreads();
  }
  // store: C/D layout col(n)=lane&15, row(m)=quad*4+reg
#pragma unroll
  for (int i = 0; i < 2; i++) {
    int cobase = co0 + wm + i * 16 + quad * 4;
#pragma unroll
    for (int j = 0; j < 2; j++) {
      int n = n0 + wn + j * 16 + l16;
#pragma unroll
      for (int r = 0; r < 4; r++)
        xout[((size_t)b * CO + cobase + r) * NPB + n] = acc[i][j][r];
    }
  }
}

// ---------------------------------------------------------------------------
// instance norm (+leaky) in place
template <int NPIX>
__global__ __launch_bounds__(256) void k_inorm(float* __restrict__ x) {
  float* p = x + (size_t)blockIdx.x * NPIX;
  float sum = 0.0f, sq = 0.0f;
  for (int i = threadIdx.x; i < NPIX; i += 256) {
    float v = p[i];
    sum += v;
    sq += v * v;
  }
#pragma unroll
  for (int o = 32; o > 0; o >>= 1) {
    sum += __shfl_down(sum, o, 64);
    sq += __shfl_down(sq, o, 64);
  }
  __shared__ float red[8];
  int wid = threadIdx.x >> 6;
  if ((threadIdx.x & 63) == 0) {
    red[wid] = sum;
    red[4 + wid] = sq;
  }
  __syncthreads();
  if (threadIdx.x == 0) {
    red[0] = red[0] + red[1] + red[2] + red[3];
    red[4] = red[4] + red[5] + red[6] + red[7];
  }
  __syncthreads();
  float m = red[0] * (1.0f / NPIX);
  float var = red[4] * (1.0f / NPIX) - m * m;
  float inv = rsqrtf(var + 1e-5f);
  for (int i = threadIdx.x; i < NPIX; i += 256) {
    float v = (p[i] - m) * inv;
    p[i] = LRELU(v);
  }
}

// ---------------------------------------------------------------------------
// 1x1 conv, register-tiled GEMM: out (B,CO,1024) = w(S,CO,128) @ x(B,128,1024)
__global__ __launch_bounds__(256) void k_conv1x1(
    const float* __restrict__ xin, const float* __restrict__ w,
    const float* __restrict__ bias, const int* __restrict__ sidx,
    float* __restrict__ out, int CO) {
  __shared__ float xsh[32 * 256];
  __shared__ float wsh[16 * 32];
  const int t = threadIdx.x;
  const int b = blockIdx.x;
  const int cow = blockIdx.y >> 2, nw = blockIdx.y & 3;
  const int co0 = cow * 16, nn0 = nw * 256;
  const int s = sidx[b];
  const int cg = t >> 6, ng = t & 63;
  const float* xb = xin + (size_t)b * 128 * 1024;
  float4 acc4[4];
#pragma unroll
  for (int c = 0; c < 4; c++) {
    float bb = bias[s * CO + co0 + cg * 4 + c];
    acc4[c] = make_float4(bb, bb, bb, bb);
  }
  for (int cc = 0; cc < 4; cc++) {
#pragma unroll
    for (int k = 0; k < 8; k++) {
      int id = t + (k << 8);
      int ci = id >> 6, nf = id & 63;
      ((float4*)xsh)[id] = ((const float4*)(xb + (cc * 32 + ci) * 1024 + nn0))[nf];
    }
    if (t < 128)
      ((float4*)wsh)[t] =
          ((const float4*)(w + ((size_t)(s * CO + co0 + (t >> 3))) * 128 + cc * 32))[t & 7];
    __syncthreads();
#pragma unroll
    for (int ci4 = 0; ci4 < 8; ci4++) {
      float4 wv[4], xv[4];
#pragma unroll
      for (int c = 0; c < 4; c++) wv[c] = ((const float4*)wsh)[(cg * 4 + c) * 8 + ci4];
#pragma unroll
      for (int i = 0; i < 4; i++) xv[i] = ((const float4*)xsh)[(ci4 * 4 + i) * 64 + ng];
#pragma unroll
      for (int c = 0; c < 4; c++)
#pragma unroll
        for (int i = 0; i < 4; i++) {
          float wvc = i == 0 ? wv[c].x : i == 1 ? wv[c].y : i == 2 ? wv[c].z : wv[c].w;
          acc4[c].x += wvc * xv[i].x;
          acc4[c].y += wvc * xv[i].y;
          acc4[c].z += wvc * xv[i].z;
          acc4[c].w += wvc * xv[i].w;
        }
    }
    __syncthreads();
  }
#pragma unroll
  for (int c = 0; c < 4; c++) {
    int co = co0 + cg * 4 + c;
    ((float4*)(out + ((size_t)b * CO + co) * 1024 + nn0))[ng] = acc4[c];
  }
}

// ---------------------------------------------------------------------------
// fused self-attention per (b, 8-n tile). Skewed-transposed scores sc[m][nl],
// register-tiled PV (8co x 8nl per thread, m split 16-way) + LDS reduction.
__device__ __forceinline__ int scidx(int m, int nl) { return m * 8 + (m & ~3) + nl; }

__global__ __launch_bounds__(256) void k_attn(
    const float* __restrict__ q, const float* __restrict__ k, const float* __restrict__ v,
    const float* __restrict__ x1, const float* __restrict__ gamma,
    const int* __restrict__ sidx, float* __restrict__ y) {
  __shared__ float sc[9216];
  __shared__ float vt[8192];
  __shared__ float ql[128];
  __shared__ float inv_s[8];
  const int t = threadIdx.x;
  const int b = blockIdx.x >> 7;
  const int n0 = (blockIdx.x & 127) << 3;
  const float* qb = q + (size_t)b * 16 * 1024;
  const float* kb = k + (size_t)b * 16 * 1024;
  const float* vb = v + (size_t)b * 128 * 1024;
  const float* xb = x1 + (size_t)b * 128 * 1024;
  if (t < 128) {
    int c = t >> 3, nl = t & 7;
    ql[c * 8 + nl] = qb[(c << 10) + n0 + nl];
  }
  __syncthreads();
  {
    float acc[4][8];
#pragma unroll
    for (int j = 0; j < 4; j++)
#pragma unroll
      for (int nl = 0; nl < 8; nl++) acc[j][nl] = 0.0f;
#pragma unroll
    for (int c = 0; c < 16; c++) {
      float4 kv = ((const float4*)(kb + (c << 10)))[t];
      float4 qa = ((const float4*)ql)[c * 2];
      float4 qbv = ((const float4*)ql)[c * 2 + 1];
#pragma unroll
      for (int j = 0; j < 4; j++) {
        float kk = j == 0 ? kv.x : j == 1 ? kv.y : j == 2 ? kv.z : kv.w;
        acc[j][0] += kk * qa.x;
        acc[j][1] += kk * qa.y;
        acc[j][2] += kk * qa.z;
        acc[j][3] += kk * qa.w;
        acc[j][4] += kk * qbv.x;
        acc[j][5] += kk * qbv.y;
        acc[j][6] += kk * qbv.z;
        acc[j][7] += kk * qbv.w;
      }
    }
#pragma unroll
    for (int j = 0; j < 4; j++) {
      int m = t * 4 + j;
      int base = scidx(m, 0) >> 2;
      ((float4*)sc)[base] = make_float4(acc[j][0], acc[j][1], acc[j][2], acc[j][3]);
      ((float4*)sc)[base + 1] = make_float4(acc[j][4], acc[j][5], acc[j][6], acc[j][7]);
    }
  }
  __syncthreads();
  {
    int nl = t >> 5, l = t & 31;
    float mx = -1e30f;
    for (int m = l; m < 1024; m += 32) mx = fmaxf(mx, sc[scidx(m, nl)]);
#pragma unroll
    for (int o = 16; o > 0; o >>= 1) mx = fmaxf(mx, __shfl_xor(mx, o, 64));
    float ssum = 0.0f;
    for (int m = l; m < 1024; m += 32) {
      float e = __expf(sc[scidx(m, nl)] - mx);
      sc[scidx(m, nl)] = e;
      ssum += e;
    }
#pragma unroll
    for (int o = 16; o > 0; o >>= 1) ssum += __shfl_xor(ssum, o, 64);
    if (l == 0) inv_s[nl] = 1.0f / ssum;
  }
  __syncthreads();
  const int cog = t >> 4, mg = t & 15;
  float4 acc4[16];
#pragma unroll
  for (int i = 0; i < 16; i++) acc4[i] = make_float4(0.f, 0.f, 0.f, 0.f);
  for (int mt = 0; mt < 1024; mt += 64) {
#pragma unroll
    for (int kk = 0; kk < 8; kk++) {
      int id = t + (kk << 8);
      int c2 = id >> 4, m4 = id & 15;
      ((float4*)vt)[id] = ((const float4*)(vb + (c2 << 10) + mt))[m4];
    }
    __syncthreads();
    float4 vt4[8];
#pragma unroll
    for (int c = 0; c < 8; c++) vt4[c] = ((const float4*)vt)[(cog * 8 + c) * 16 + mg];
#pragma unroll
    for (int j = 0; j < 4; j++) {
      int m = mt + mg * 4 + j;
      int base = scidx(m, 0) >> 2;
      float4 s0 = ((const float4*)sc)[base];
      float4 s1 = ((const float4*)sc)[base + 1];
#pragma unroll
      for (int c = 0; c < 8; c++) {
        float vv = j == 0 ? vt4[c].x : j == 1 ? vt4[c].y : j == 2 ? vt4[c].z : vt4[c].w;
        acc4[c * 2].x += vv * s0.x;
        acc4[c * 2].y += vv * s0.y;
        acc4[c * 2].z += vv * s0.z;
        acc4[c * 2].w += vv * s0.w;
        acc4[c * 2 + 1].x += vv * s1.x;
        acc4[c * 2 + 1].y += vv * s1.y;
        acc4[c * 2 + 1].z += vv * s1.z;
        acc4[c * 2 + 1].w += vv * s1.w;
      }
    }
    __syncthreads();
  }
  for (int h = 8; h >= 1; h >>= 1) {
    if (mg >= h && mg < 2 * h) {
      int base = ((mg - h) * 16 + cog) * 16;
#pragma unroll
      for (int kk = 0; kk < 16; kk++) ((float4*)sc)[base + kk] = acc4[kk];
    }
    __syncthreads();
    if (mg < h) {
      int base = (mg * 16 + cog) * 16;
#pragma unroll
      for (int kk = 0; kk < 16; kk++) {
        float4 o = ((const float4*)sc)[base + kk];
        acc4[kk].x += o.x;
        acc4[kk].y += o.y;
        acc4[kk].z += o.z;
        acc4[kk].w += o.w;
      }
    }
    __syncthreads();
  }
  if (mg == 0) {
#pragma unroll
    for (int kk = 0; kk < 16; kk++) ((float4*)sc)[cog * 16 + kk] = acc4[kk];
  }
  __syncthreads();
  {
    float g = gamma[sidx[b]];
    float4 val = ((const float4*)sc)[t];
#pragma unroll
    for (int ii = 0; ii < 4; ii++) {
      int id = t * 4 + ii;
      int co = id >> 3, nl = id & 7;
      float vv = ii == 0 ? val.x : ii == 1 ? val.y : ii == 2 ? val.z : val.w;
      int n = n0 + nl;
      y[(((size_t)b * 128 + co) << 10) + n] = g * vv * inv_s[nl] + xb[(co << 10) + n];
    }
  }
}

// ---------------------------------------------------------------------------
// head: x2 (B,256,16,16) -> out (B,1,15,15), k4 s1 p1, +bias
__global__ __launch_bounds__(256) void k_head(
    const float* __restrict__ x2, const float* __restrict__ wh,
    const float* __restrict__ bh, const int* __restrict__ sidx,
    float* __restrict__ out) {
  int bp = blockIdx.x;
  int b = bp / 225, pix = bp % 225;
  int oh = pix / 15, ow = pix % 15;
  int s = sidx[b];
  int ci = threadIdx.x;
  const float* xp = x2 + (((size_t)b * 256 + ci) << 8);
  const float* wp = wh + s * 4096 + ci * 16;
  float acc = 0.0f;
#pragma unroll
  for (int kh = 0; kh < 4; kh++) {
    int ih = oh - 1 + kh;
    if ((unsigned)ih >= 16u) continue;
#pragma unroll
    for (int kw = 0; kw < 4; kw++) {
      int iw = ow - 1 + kw;
      if ((unsigned)iw >= 16u) continue;
      acc += wp[kh * 4 + kw] * xp[(ih << 4) + iw];
    }
  }
#pragma unroll
  for (int o = 32; o > 0; o >>= 1) acc += __shfl_down(acc, o, 64);
  __shared__ float red[4];
  if ((threadIdx.x & 63) == 0) red[threadIdx.x >> 6] = acc;
  __syncthreads();
  if (threadIdx.x == 0) {
    float r = red[0] + red[1] + red[2] + red[3] + bh[s];
    out[b * 225 + pix] = r;
  }
}

// ---------------------------------------------------------------------------
extern "C" void kernel_launch(void* const* d_in, const int* in_sizes, int n_in,
                              void* d_out, int out_size, void* d_ws, size_t ws_size,
                              hipStream_t stream) {
  const float* img = (const float*)d_in[0];
  const int* sidx = (const int*)d_in[1];
  const float* w0 = (const float*)d_in[2];
  const float* b0 = (const float*)d_in[3];
  const float* w1 = (const float*)d_in[4];
  const float* w2 = (const float*)d_in[6];
  const float* wq = (const float*)d_in[8];
  const float* bq = (const float*)d_in[9];
  const float* wk = (const float*)d_in[10];
  const float* bk = (const float*)d_in[11];
  const float* wv = (const float*)d_in[12];
  const float* bv = (const float*)d_in[13];
  const float* gamma = (const float*)d_in[14];
  const float* wh = (const float*)d_in[15];
  const float* bh = (const float*)d_in[16];
  float* out = (float*)d_out;

  float* ws = (float*)d_ws;
  float* x0 = ws + 0;        // (B,64,64,64)
  float* x1 = ws + 4194304;  // (B,128,32,32)
  float* q = ws + 6291456;   // (B,16,1024)
  float* k = ws + 6553600;
  float* v = ws + 6815744;   // (B,128,1024)
  float* x2 = ws + 8912896;  // (B,256,16,16)
  float* y = x0;             // alias, x0 dead after conv1

  const int B = 16;

  k_conv0<<<dim3(B * 64, 16), 256, 0, stream>>>(img, w0, b0, sidx, x0);
  // conv1: CI=64, CO=128, HIN=64 (OW=32); bias skipped (inorm cancels it)
  k_conv_mfma<64, 128, 64, 5><<<dim3(B, 32), 256, 0, stream>>>(x0, w1, sidx, x1);
  k_inorm<1024><<<B * 128, 256, 0, stream>>>(x1);
  k_conv1x1<<<dim3(B, 4), 256, 0, stream>>>(x1, wq, bq, sidx, q, 16);
  k_conv1x1<<<dim3(B, 4), 256, 0, stream>>>(x1, wk, bk, sidx, k, 16);
  k_conv1x1<<<dim3(B, 32), 256, 0, stream>>>(x1, wv, bv, sidx, v, 128);
  k_attn<<<B * 128, 256, 0, stream>>>(q, k, v, x1, gamma, sidx, y);
  // conv2: CI=128, CO=256, HIN=32 (OW=16); bias skipped (inorm cancels it)
  k_conv_mfma<128, 256, 32, 4><<<dim3(B, 16), 256, 0, stream>>>(y, w2, sidx, x2);
  k_inorm<256><<<B * 256, 256, 0, stream>>>(x2);
  k_head<<<B * 225, 256, 0, stream>>>(x2, wh, bh, sidx, out);
}

// Round 6
// 435.332 us; speedup vs baseline: 6.2184x; 1.1087x over previous
//
#include <hip/hip_runtime.h>

#define LRELU(x) ((x) > 0.0f ? (x) : 0.2f * (x))

typedef short bf16x8 __attribute__((ext_vector_type(8)));
typedef short bf16x4 __attribute__((ext_vector_type(4)));
typedef float f32x4 __attribute__((ext_vector_type(4)));

__device__ __forceinline__ short f2bf(float f) {
  union { float f; unsigned u; } x{f};
  return (short)((x.u + 0x7FFF + ((x.u >> 16) & 1)) >> 16);
}

// ---------------------------------------------------------------------------
// conv0: img (B,1,128,128) -> x0 (B,64,64,64), k4 s2 p1, +bias, +leaky
__global__ __launch_bounds__(256) void k_conv0(
    const float* __restrict__ img, const float* __restrict__ w0,
    const float* __restrict__ b0, const int* __restrict__ sidx,
    float* __restrict__ x0) {
  int bc = blockIdx.x;
  int b = bc >> 6, co = bc & 63;
  int pix = blockIdx.y * 256 + threadIdx.x;
  int oh = pix >> 6, ow = pix & 63;
  int s = sidx[b];
  const float* w = w0 + (s * 64 + co) * 16;
  float wr[16];
#pragma unroll
  for (int i = 0; i < 16; i++) wr[i] = w[i];
  float acc = b0[s * 64 + co];
  const float* ip = img + (size_t)b * 128 * 128;
  int ih0 = oh * 2 - 1, iw0 = ow * 2 - 1;
#pragma unroll
  for (int kh = 0; kh < 4; kh++) {
    int ih = ih0 + kh;
    if ((unsigned)ih >= 128u) continue;
#pragma unroll
    for (int kw = 0; kw < 4; kw++) {
      int iw = iw0 + kw;
      if ((unsigned)iw >= 128u) continue;
      acc += wr[kh * 4 + kw] * ip[ih * 128 + iw];
    }
  }
  x0[(((size_t)b * 64 + co) << 12) + pix] = LRELU(acc);
}

// ---------------------------------------------------------------------------
// MFMA implicit-GEMM k4s2p1 conv (NO bias - cancelled by following inorm).
template <int CI, int CO, int HIN, int OWSHIFT>
__global__ __launch_bounds__(256) void k_conv_mfma(
    const float* __restrict__ xin, const float* __restrict__ wgt,
    const int* __restrict__ sidx, float* __restrict__ xout) {
  constexpr int WIN = HIN;
  constexpr int OW = 1 << OWSHIFT;
  constexpr int OH = HIN / 2;
  constexpr int NPB = OH * OW;
  constexpr int NT = NPB / 64;
  constexpr int KCH = CI / 2;
  __shared__ __align__(16) short Ash[64 * 40];
  __shared__ __align__(16) short Bsh[64 * 40];
  const int t = threadIdx.x;
  const int b = blockIdx.x;
  const int co0 = (blockIdx.y / NT) * 64;
  const int n0 = (blockIdx.y % NT) * 64;
  const int s = sidx[b];
  const int lane = t & 63, wv = t >> 6;
  const int wm = (wv >> 1) * 32, wn = (wv & 1) * 32;
  const int quad = lane >> 4, l16 = lane & 15;

  const int arow = t & 63, ag = t >> 6;
  const float* wrow = wgt + ((size_t)(s * CO + co0 + arow)) * (CI * 16) + ag * 8;
  const int bn = t & 63, bg = t >> 6;
  const int p = n0 + bn;
  const int oh = p >> OWSHIFT, ow = p & (OW - 1);
  const int iw0 = 2 * ow - 1;
  const int ihb = 2 * oh - 1 + (bg & 1) * 2;
  const float* xb = xin + ((size_t)b * CI + (bg >> 1)) * (HIN * WIN);

  f32x4 acc[2][2];
#pragma unroll
  for (int i = 0; i < 2; i++)
#pragma unroll
    for (int j = 0; j < 2; j++) acc[i][j] = (f32x4){0.f, 0.f, 0.f, 0.f};

  for (int kc = 0; kc < KCH; kc++) {
    {
      const float* wp = wrow + kc * 32;
      float4 f0 = *(const float4*)wp;
      float4 f1 = *(const float4*)(wp + 4);
      bf16x8 av;
      av[0] = f2bf(f0.x); av[1] = f2bf(f0.y); av[2] = f2bf(f0.z); av[3] = f2bf(f0.w);
      av[4] = f2bf(f1.x); av[5] = f2bf(f1.y); av[6] = f2bf(f1.z); av[7] = f2bf(f1.w);
      *(bf16x8*)&Ash[arow * 40 + ag * 8] = av;
    }
    {
      const float* yp = xb + (size_t)kc * 2 * (HIN * WIN);
      bf16x8 bv;
#pragma unroll
      for (int r = 0; r < 2; r++) {
        int ih = ihb + r;
        bool rok = (unsigned)ih < (unsigned)HIN;
        const float* rp = yp + ih * WIN;
#pragma unroll
        for (int kwi = 0; kwi < 4; kwi++) {
          int iw = iw0 + kwi;
          float f = (rok && (unsigned)iw < (unsigned)WIN) ? rp[iw] : 0.0f;
          bv[r * 4 + kwi] = f2bf(f);
        }
      }
      *(bf16x8*)&Bsh[bn * 40 + bg * 8] = bv;
    }
    __syncthreads();
    bf16x8 af[2], bfv[2];
#pragma unroll
    for (int i = 0; i < 2; i++)
      af[i] = *(const bf16x8*)&Ash[(wm + i * 16 + l16) * 40 + quad * 8];
#pragma unroll
    for (int j = 0; j < 2; j++)
      bfv[j] = *(const bf16x8*)&Bsh[(wn + j * 16 + l16) * 40 + quad * 8];
#pragma unroll
    for (int i = 0; i < 2; i++)
#pragma unroll
      for (int j = 0; j < 2; j++)
        acc[i][j] = __builtin_amdgcn_mfma_f32_16x16x32_bf16(af[i], bfv[j], acc[i][j], 0, 0, 0);
    __syncthreads();
  }
#pragma unroll
  for (int i = 0; i < 2; i++) {
    int cobase = co0 + wm + i * 16 + quad * 4;
#pragma unroll
    for (int j = 0; j < 2; j++) {
      int n = n0 + wn + j * 16 + l16;
#pragma unroll
      for (int r = 0; r < 4; r++)
        xout[((size_t)b * CO + cobase + r) * NPB + n] = acc[i][j][r];
    }
  }
}

// ---------------------------------------------------------------------------
// instance norm (+leaky) in place
template <int NPIX>
__global__ __launch_bounds__(256) void k_inorm(float* __restrict__ x) {
  float* p = x + (size_t)blockIdx.x * NPIX;
  float sum = 0.0f, sq = 0.0f;
  for (int i = threadIdx.x; i < NPIX; i += 256) {
    float v = p[i];
    sum += v;
    sq += v * v;
  }
#pragma unroll
  for (int o = 32; o > 0; o >>= 1) {
    sum += __shfl_down(sum, o, 64);
    sq += __shfl_down(sq, o, 64);
  }
  __shared__ float red[8];
  int wid = threadIdx.x >> 6;
  if ((threadIdx.x & 63) == 0) {
    red[wid] = sum;
    red[4 + wid] = sq;
  }
  __syncthreads();
  if (threadIdx.x == 0) {
    red[0] = red[0] + red[1] + red[2] + red[3];
    red[4] = red[4] + red[5] + red[6] + red[7];
  }
  __syncthreads();
  float m = red[0] * (1.0f / NPIX);
  float var = red[4] * (1.0f / NPIX) - m * m;
  float inv = rsqrtf(var + 1e-5f);
  for (int i = threadIdx.x; i < NPIX; i += 256) {
    float v = (p[i] - m) * inv;
    p[i] = LRELU(v);
  }
}

// ---------------------------------------------------------------------------
// 1x1 conv, register-tiled GEMM
__global__ __launch_bounds__(256) void k_conv1x1(
    const float* __restrict__ xin, const float* __restrict__ w,
    const float* __restrict__ bias, const int* __restrict__ sidx,
    float* __restrict__ out, int CO) {
  __shared__ float xsh[32 * 256];
  __shared__ float wsh[16 * 32];
  const int t = threadIdx.x;
  const int b = blockIdx.x;
  const int cow = blockIdx.y >> 2, nw = blockIdx.y & 3;
  const int co0 = cow * 16, nn0 = nw * 256;
  const int s = sidx[b];
  const int cg = t >> 6, ng = t & 63;
  const float* xb = xin + (size_t)b * 128 * 1024;
  float4 acc4[4];
#pragma unroll
  for (int c = 0; c < 4; c++) {
    float bb = bias[s * CO + co0 + cg * 4 + c];
    acc4[c] = make_float4(bb, bb, bb, bb);
  }
  for (int cc = 0; cc < 4; cc++) {
#pragma unroll
    for (int k = 0; k < 8; k++) {
      int id = t + (k << 8);
      int ci = id >> 6, nf = id & 63;
      ((float4*)xsh)[id] = ((const float4*)(xb + (cc * 32 + ci) * 1024 + nn0))[nf];
    }
    if (t < 128)
      ((float4*)wsh)[t] =
          ((const float4*)(w + ((size_t)(s * CO + co0 + (t >> 3))) * 128 + cc * 32))[t & 7];
    __syncthreads();
#pragma unroll
    for (int ci4 = 0; ci4 < 8; ci4++) {
      float4 wv[4], xv[4];
#pragma unroll
      for (int c = 0; c < 4; c++) wv[c] = ((const float4*)wsh)[(cg * 4 + c) * 8 + ci4];
#pragma unroll
      for (int i = 0; i < 4; i++) xv[i] = ((const float4*)xsh)[(ci4 * 4 + i) * 64 + ng];
#pragma unroll
      for (int c = 0; c < 4; c++)
#pragma unroll
        for (int i = 0; i < 4; i++) {
          float wvc = i == 0 ? wv[c].x : i == 1 ? wv[c].y : i == 2 ? wv[c].z : wv[c].w;
          acc4[c].x += wvc * xv[i].x;
          acc4[c].y += wvc * xv[i].y;
          acc4[c].z += wvc * xv[i].z;
          acc4[c].w += wvc * xv[i].w;
        }
    }
    __syncthreads();
  }
#pragma unroll
  for (int c = 0; c < 4; c++) {
    int co = co0 + cg * 4 + c;
    ((float4*)(out + ((size_t)b * CO + co) * 1024 + nn0))[ng] = acc4[c];
  }
}

// ---------------------------------------------------------------------------
// fused self-attention, MFMA PV. grid (B*64): b = bx>>6, n-tile 16 = (bx&63)*16.
// Phase 1: scores fp32 (thread: 4m x 16nl), softmax from registers (shuffle +
// cross-wave LDS), P stored UNNORMALIZED as bf16 B-operand [n][m-contig];
// normalization folded into epilogue. Phase 2: V chunks staged as bf16
// A-operand [co][m-contig], 2 mfma_16x16x32 per wave per 32-m chunk.
__global__ __launch_bounds__(256) void k_attn(
    const float* __restrict__ q, const float* __restrict__ k, const float* __restrict__ v,
    const float* __restrict__ x1, const float* __restrict__ gamma,
    const int* __restrict__ sidx, float* __restrict__ y) {
  __shared__ __align__(16) short Psh[16 * 1032];  // 33 KB bf16 P^T [nl][m]
  __shared__ __align__(16) short Ash[128 * 40];   // 10 KB bf16 V [co][m-chunk]
  __shared__ float qsh[256];                      // [c][nl]
  __shared__ float redm[64], reds[64], sums[16];
  const int t = threadIdx.x;
  const int b = blockIdx.x >> 6;
  const int n0 = (blockIdx.x & 63) << 4;
  const int lane = t & 63, wv = t >> 6;
  const int quad = lane >> 4, l16 = lane & 15;
  const float* qb = q + (size_t)b * 16 * 1024;
  const float* kb = k + (size_t)b * 16 * 1024;
  const float* vb = v + (size_t)b * 128 * 1024;
  const float* xb = x1 + (size_t)b * 128 * 1024;

  qsh[t] = qb[((t >> 4) << 10) + n0 + (t & 15)];
  __syncthreads();

  // ---- scores: thread handles m = 4t..4t+3, all 16 nl
  float acc[4][16];
#pragma unroll
  for (int j = 0; j < 4; j++)
#pragma unroll
    for (int nl = 0; nl < 16; nl++) acc[j][nl] = 0.0f;
#pragma unroll
  for (int c = 0; c < 16; c++) {
    float4 kv = *(const float4*)(kb + (c << 10) + 4 * t);
    const float* qr = qsh + c * 16;
#pragma unroll
    for (int j = 0; j < 4; j++) {
      float kk = j == 0 ? kv.x : j == 1 ? kv.y : j == 2 ? kv.z : kv.w;
#pragma unroll
      for (int nl = 0; nl < 16; nl++) acc[j][nl] += kk * qr[nl];
    }
  }
  // ---- per-nl max over all m
  float lmax[16];
#pragma unroll
  for (int nl = 0; nl < 16; nl++)
    lmax[nl] = fmaxf(fmaxf(acc[0][nl], acc[1][nl]), fmaxf(acc[2][nl], acc[3][nl]));
#pragma unroll
  for (int o = 32; o > 0; o >>= 1)
#pragma unroll
    for (int nl = 0; nl < 16; nl++) lmax[nl] = fmaxf(lmax[nl], __shfl_xor(lmax[nl], o, 64));
  if (lane == 0)
#pragma unroll
    for (int nl = 0; nl < 16; nl++) redm[wv * 16 + nl] = lmax[nl];
  __syncthreads();
#pragma unroll
  for (int nl = 0; nl < 16; nl++)
    lmax[nl] = fmaxf(fmaxf(redm[nl], redm[16 + nl]), fmaxf(redm[32 + nl], redm[48 + nl]));
  // ---- exp (unnormalized) + per-nl sum
  float lsum[16];
#pragma unroll
  for (int nl = 0; nl < 16; nl++) lsum[nl] = 0.0f;
#pragma unroll
  for (int j = 0; j < 4; j++)
#pragma unroll
    for (int nl = 0; nl < 16; nl++) {
      float e = __expf(acc[j][nl] - lmax[nl]);
      acc[j][nl] = e;
      lsum[nl] += e;
    }
#pragma unroll
  for (int o = 32; o > 0; o >>= 1)
#pragma unroll
    for (int nl = 0; nl < 16; nl++) lsum[nl] += __shfl_xor(lsum[nl], o, 64);
  if (lane == 0)
#pragma unroll
    for (int nl = 0; nl < 16; nl++) reds[wv * 16 + nl] = lsum[nl];
  // ---- write P^T bf16 (m-contig per nl row)
#pragma unroll
  for (int nl = 0; nl < 16; nl++) {
    bf16x4 pv;
    pv[0] = f2bf(acc[0][nl]);
    pv[1] = f2bf(acc[1][nl]);
    pv[2] = f2bf(acc[2][nl]);
    pv[3] = f2bf(acc[3][nl]);
    *(bf16x4*)&Psh[nl * 1032 + 4 * t] = pv;
  }
  __syncthreads();
  if (t < 16) sums[t] = reds[t] + reds[16 + t] + reds[32 + t] + reds[48 + t];

  // ---- PV: wave wv owns co tiles [wv*32, wv*32+16); N = 16 (this n-tile)
  const int sco = t & 127, shalf = t >> 7;
  const float* vrow = vb + ((size_t)sco << 10) + shalf * 16;
  short* arow = Ash + sco * 40 + shalf * 16;
  f32x4 dacc[2];
  dacc[0] = (f32x4){0.f, 0.f, 0.f, 0.f};
  dacc[1] = (f32x4){0.f, 0.f, 0.f, 0.f};
  for (int mt = 0; mt < 1024; mt += 32) {
    float4 f0 = *(const float4*)(vrow + mt);
    float4 f1 = *(const float4*)(vrow + mt + 4);
    float4 f2 = *(const float4*)(vrow + mt + 8);
    float4 f3 = *(const float4*)(vrow + mt + 12);
    bf16x8 a0, a1;
    a0[0] = f2bf(f0.x); a0[1] = f2bf(f0.y); a0[2] = f2bf(f0.z); a0[3] = f2bf(f0.w);
    a0[4] = f2bf(f1.x); a0[5] = f2bf(f1.y); a0[6] = f2bf(f1.z); a0[7] = f2bf(f1.w);
    a1[0] = f2bf(f2.x); a1[1] = f2bf(f2.y); a1[2] = f2bf(f2.z); a1[3] = f2bf(f2.w);
    a1[4] = f2bf(f3.x); a1[5] = f2bf(f3.y); a1[6] = f2bf(f3.z); a1[7] = f2bf(f3.w);
    *(bf16x8*)arow = a0;
    *(bf16x8*)(arow + 8) = a1;
    __syncthreads();
    bf16x8 af0 = *(const bf16x8*)&Ash[(wv * 32 + l16) * 40 + quad * 8];
    bf16x8 af1 = *(const bf16x8*)&Ash[(wv * 32 + 16 + l16) * 40 + quad * 8];
    bf16x8 bf = *(const bf16x8*)&Psh[l16 * 1032 + mt + quad * 8];
    dacc[0] = __builtin_amdgcn_mfma_f32_16x16x32_bf16(af0, bf, dacc[0], 0, 0, 0);
    dacc[1] = __builtin_amdgcn_mfma_f32_16x16x32_bf16(af1, bf, dacc[1], 0, 0, 0);
    __syncthreads();
  }
  // ---- epilogue: normalize, gamma, residual. C/D: col(n)=l16, row=quad*4+r
  float g = gamma[sidx[b]];
  float rs = 1.0f / sums[l16];
  int n = n0 + l16;
#pragma unroll
  for (int i = 0; i < 2; i++) {
    int cob = wv * 32 + i * 16 + quad * 4;
#pragma unroll
    for (int r = 0; r < 4; r++) {
      int co = cob + r;
      y[(((size_t)b * 128 + co) << 10) + n] = g * dacc[i][r] * rs + xb[(co << 10) + n];
    }
  }
}

// ---------------------------------------------------------------------------
// head: x2 (B,256,16,16) -> out (B,1,15,15), k4 s1 p1, +bias
__global__ __launch_bounds__(256) void k_head(
    const float* __restrict__ x2, const float* __restrict__ wh,
    const float* __restrict__ bh, const int* __restrict__ sidx,
    float* __restrict__ out) {
  int bp = blockIdx.x;
  int b = bp / 225, pix = bp % 225;
  int oh = pix / 15, ow = pix % 15;
  int s = sidx[b];
  int ci = threadIdx.x;
  const float* xp = x2 + (((size_t)b * 256 + ci) << 8);
  const float* wp = wh + s * 4096 + ci * 16;
  float acc = 0.0f;
#pragma unroll
  for (int kh = 0; kh < 4; kh++) {
    int ih = oh - 1 + kh;
    if ((unsigned)ih >= 16u) continue;
#pragma unroll
    for (int kw = 0; kw < 4; kw++) {
      int iw = ow - 1 + kw;
      if ((unsigned)iw >= 16u) continue;
      acc += wp[kh * 4 + kw] * xp[(ih << 4) + iw];
    }
  }
#pragma unroll
  for (int o = 32; o > 0; o >>= 1) acc += __shfl_down(acc, o, 64);
  __shared__ float red[4];
  if ((threadIdx.x & 63) == 0) red[threadIdx.x >> 6] = acc;
  __syncthreads();
  if (threadIdx.x == 0) {
    float r = red[0] + red[1] + red[2] + red[3] + bh[s];
    out[b * 225 + pix] = r;
  }
}

// ---------------------------------------------------------------------------
extern "C" void kernel_launch(void* const* d_in, const int* in_sizes, int n_in,
                              void* d_out, int out_size, void* d_ws, size_t ws_size,
                              hipStream_t stream) {
  const float* img = (const float*)d_in[0];
  const int* sidx = (const int*)d_in[1];
  const float* w0 = (const float*)d_in[2];
  const float* b0 = (const float*)d_in[3];
  const float* w1 = (const float*)d_in[4];
  const float* w2 = (const float*)d_in[6];
  const float* wq = (const float*)d_in[8];
  const float* bq = (const float*)d_in[9];
  const float* wk = (const float*)d_in[10];
  const float* bk = (const float*)d_in[11];
  const float* wv = (const float*)d_in[12];
  const float* bv = (const float*)d_in[13];
  const float* gamma = (const float*)d_in[14];
  const float* wh = (const float*)d_in[15];
  const float* bh = (const float*)d_in[16];
  float* out = (float*)d_out;

  float* ws = (float*)d_ws;
  float* x0 = ws + 0;        // (B,64,64,64)
  float* x1 = ws + 4194304;  // (B,128,32,32)
  float* q = ws + 6291456;   // (B,16,1024)
  float* k = ws + 6553600;
  float* v = ws + 6815744;   // (B,128,1024)
  float* x2 = ws + 8912896;  // (B,256,16,16)
  float* y = x0;             // alias, x0 dead after conv1

  const int B = 16;

  k_conv0<<<dim3(B * 64, 16), 256, 0, stream>>>(img, w0, b0, sidx, x0);
  k_conv_mfma<64, 128, 64, 5><<<dim3(B, 32), 256, 0, stream>>>(x0, w1, sidx, x1);
  k_inorm<1024><<<B * 128, 256, 0, stream>>>(x1);
  k_conv1x1<<<dim3(B, 4), 256, 0, stream>>>(x1, wq, bq, sidx, q, 16);
  k_conv1x1<<<dim3(B, 4), 256, 0, stream>>>(x1, wk, bk, sidx, k, 16);
  k_conv1x1<<<dim3(B, 32), 256, 0, stream>>>(x1, wv, bv, sidx, v, 128);
  k_attn<<<B * 64, 256, 0, stream>>>(q, k, v, x1, gamma, sidx, y);
  k_conv_mfma<128, 256, 32, 4><<<dim3(B, 16), 256, 0, stream>>>(y, w2, sidx, x2);
  k_inorm<256><<<B * 256, 256, 0, stream>>>(x2);
  k_head<<<B * 225, 256, 0, stream>>>(x2, wh, bh, sidx, out);
}

// Round 7
// 392.958 us; speedup vs baseline: 6.8890x; 1.1078x over previous
//
#include <hip/hip_runtime.h>

#define LRELU(x) ((x) > 0.0f ? (x) : 0.2f * (x))

typedef short bf16x8 __attribute__((ext_vector_type(8)));
typedef short bf16x4 __attribute__((ext_vector_type(4)));
typedef float f32x4 __attribute__((ext_vector_type(4)));

__device__ __forceinline__ short f2bf(float f) {
  union { float f; unsigned u; } x{f};
  return (short)((x.u + 0x7FFF + ((x.u >> 16) & 1)) >> 16);
}

// ---------------------------------------------------------------------------
// conv0: img (B,1,128,128) -> x0 (B,64,64,64), k4 s2 p1, +bias, +leaky
__global__ __launch_bounds__(256) void k_conv0(
    const float* __restrict__ img, const float* __restrict__ w0,
    const float* __restrict__ b0, const int* __restrict__ sidx,
    float* __restrict__ x0) {
  int bc = blockIdx.x;
  int b = bc >> 6, co = bc & 63;
  int pix = blockIdx.y * 256 + threadIdx.x;
  int oh = pix >> 6, ow = pix & 63;
  int s = sidx[b];
  const float* w = w0 + (s * 64 + co) * 16;
  float wr[16];
#pragma unroll
  for (int i = 0; i < 16; i++) wr[i] = w[i];
  float acc = b0[s * 64 + co];
  const float* ip = img + (size_t)b * 128 * 128;
  int ih0 = oh * 2 - 1, iw0 = ow * 2 - 1;
#pragma unroll
  for (int kh = 0; kh < 4; kh++) {
    int ih = ih0 + kh;
    if ((unsigned)ih >= 128u) continue;
#pragma unroll
    for (int kw = 0; kw < 4; kw++) {
      int iw = iw0 + kw;
      if ((unsigned)iw >= 128u) continue;
      acc += wr[kh * 4 + kw] * ip[ih * 128 + iw];
    }
  }
  x0[(((size_t)b * 64 + co) << 12) + pix] = LRELU(acc);
}

// ---------------------------------------------------------------------------
// MFMA implicit-GEMM k4s2p1 conv (NO bias - cancelled by following inorm).
template <int CI, int CO, int HIN, int OWSHIFT>
__global__ __launch_bounds__(256) void k_conv_mfma(
    const float* __restrict__ xin, const float* __restrict__ wgt,
    const int* __restrict__ sidx, float* __restrict__ xout) {
  constexpr int WIN = HIN;
  constexpr int OW = 1 << OWSHIFT;
  constexpr int OH = HIN / 2;
  constexpr int NPB = OH * OW;
  constexpr int NT = NPB / 64;
  constexpr int KCH = CI / 2;
  __shared__ __align__(16) short Ash[64 * 40];
  __shared__ __align__(16) short Bsh[64 * 40];
  const int t = threadIdx.x;
  const int b = blockIdx.x;
  const int co0 = (blockIdx.y / NT) * 64;
  const int n0 = (blockIdx.y % NT) * 64;
  const int s = sidx[b];
  const int lane = t & 63, wv = t >> 6;
  const int wm = (wv >> 1) * 32, wn = (wv & 1) * 32;
  const int quad = lane >> 4, l16 = lane & 15;

  const int arow = t & 63, ag = t >> 6;
  const float* wrow = wgt + ((size_t)(s * CO + co0 + arow)) * (CI * 16) + ag * 8;
  const int bn = t & 63, bg = t >> 6;
  const int p = n0 + bn;
  const int oh = p >> OWSHIFT, ow = p & (OW - 1);
  const int iw0 = 2 * ow - 1;
  const int ihb = 2 * oh - 1 + (bg & 1) * 2;
  const float* xb = xin + ((size_t)b * CI + (bg >> 1)) * (HIN * WIN);

  f32x4 acc[2][2];
#pragma unroll
  for (int i = 0; i < 2; i++)
#pragma unroll
    for (int j = 0; j < 2; j++) acc[i][j] = (f32x4){0.f, 0.f, 0.f, 0.f};

  for (int kc = 0; kc < KCH; kc++) {
    {
      const float* wp = wrow + kc * 32;
      float4 f0 = *(const float4*)wp;
      float4 f1 = *(const float4*)(wp + 4);
      bf16x8 av;
      av[0] = f2bf(f0.x); av[1] = f2bf(f0.y); av[2] = f2bf(f0.z); av[3] = f2bf(f0.w);
      av[4] = f2bf(f1.x); av[5] = f2bf(f1.y); av[6] = f2bf(f1.z); av[7] = f2bf(f1.w);
      *(bf16x8*)&Ash[arow * 40 + ag * 8] = av;
    }
    {
      const float* yp = xb + (size_t)kc * 2 * (HIN * WIN);
      bf16x8 bv;
#pragma unroll
      for (int r = 0; r < 2; r++) {
        int ih = ihb + r;
        bool rok = (unsigned)ih < (unsigned)HIN;
        const float* rp = yp + ih * WIN;
#pragma unroll
        for (int kwi = 0; kwi < 4; kwi++) {
          int iw = iw0 + kwi;
          float f = (rok && (unsigned)iw < (unsigned)WIN) ? rp[iw] : 0.0f;
          bv[r * 4 + kwi] = f2bf(f);
        }
      }
      *(bf16x8*)&Bsh[bn * 40 + bg * 8] = bv;
    }
    __syncthreads();
    bf16x8 af[2], bfv[2];
#pragma unroll
    for (int i = 0; i < 2; i++)
      af[i] = *(const bf16x8*)&Ash[(wm + i * 16 + l16) * 40 + quad * 8];
#pragma unroll
    for (int j = 0; j < 2; j++)
      bfv[j] = *(const bf16x8*)&Bsh[(wn + j * 16 + l16) * 40 + quad * 8];
#pragma unroll
    for (int i = 0; i < 2; i++)
#pragma unroll
      for (int j = 0; j < 2; j++)
        acc[i][j] = __builtin_amdgcn_mfma_f32_16x16x32_bf16(af[i], bfv[j], acc[i][j], 0, 0, 0);
    __syncthreads();
  }
#pragma unroll
  for (int i = 0; i < 2; i++) {
    int cobase = co0 + wm + i * 16 + quad * 4;
#pragma unroll
    for (int j = 0; j < 2; j++) {
      int n = n0 + wn + j * 16 + l16;
#pragma unroll
      for (int r = 0; r < 4; r++)
        xout[((size_t)b * CO + cobase + r) * NPB + n] = acc[i][j][r];
    }
  }
}

// ---------------------------------------------------------------------------
// instance norm (+leaky) in place
template <int NPIX>
__global__ __launch_bounds__(256) void k_inorm(float* __restrict__ x) {
  float* p = x + (size_t)blockIdx.x * NPIX;
  float sum = 0.0f, sq = 0.0f;
  for (int i = threadIdx.x; i < NPIX; i += 256) {
    float v = p[i];
    sum += v;
    sq += v * v;
  }
#pragma unroll
  for (int o = 32; o > 0; o >>= 1) {
    sum += __shfl_down(sum, o, 64);
    sq += __shfl_down(sq, o, 64);
  }
  __shared__ float red[8];
  int wid = threadIdx.x >> 6;
  if ((threadIdx.x & 63) == 0) {
    red[wid] = sum;
    red[4 + wid] = sq;
  }
  __syncthreads();
  if (threadIdx.x == 0) {
    red[0] = red[0] + red[1] + red[2] + red[3];
    red[4] = red[4] + red[5] + red[6] + red[7];
  }
  __syncthreads();
  float m = red[0] * (1.0f / NPIX);
  float var = red[4] * (1.0f / NPIX) - m * m;
  float inv = rsqrtf(var + 1e-5f);
  for (int i = threadIdx.x; i < NPIX; i += 256) {
    float v = (p[i] - m) * inv;
    p[i] = LRELU(v);
  }
}

// ---------------------------------------------------------------------------
// 1x1 conv, register-tiled GEMM, fp32 out
__global__ __launch_bounds__(256) void k_conv1x1(
    const float* __restrict__ xin, const float* __restrict__ w,
    const float* __restrict__ bias, const int* __restrict__ sidx,
    float* __restrict__ out, int CO) {
  __shared__ float xsh[32 * 256];
  __shared__ float wsh[16 * 32];
  const int t = threadIdx.x;
  const int b = blockIdx.x;
  const int cow = blockIdx.y >> 2, nw = blockIdx.y & 3;
  const int co0 = cow * 16, nn0 = nw * 256;
  const int s = sidx[b];
  const int cg = t >> 6, ng = t & 63;
  const float* xb = xin + (size_t)b * 128 * 1024;
  float4 acc4[4];
#pragma unroll
  for (int c = 0; c < 4; c++) {
    float bb = bias[s * CO + co0 + cg * 4 + c];
    acc4[c] = make_float4(bb, bb, bb, bb);
  }
  for (int cc = 0; cc < 4; cc++) {
#pragma unroll
    for (int k = 0; k < 8; k++) {
      int id = t + (k << 8);
      int ci = id >> 6, nf = id & 63;
      ((float4*)xsh)[id] = ((const float4*)(xb + (cc * 32 + ci) * 1024 + nn0))[nf];
    }
    if (t < 128)
      ((float4*)wsh)[t] =
          ((const float4*)(w + ((size_t)(s * CO + co0 + (t >> 3))) * 128 + cc * 32))[t & 7];
    __syncthreads();
#pragma unroll
    for (int ci4 = 0; ci4 < 8; ci4++) {
      float4 wv[4], xv[4];
#pragma unroll
      for (int c = 0; c < 4; c++) wv[c] = ((const float4*)wsh)[(cg * 4 + c) * 8 + ci4];
#pragma unroll
      for (int i = 0; i < 4; i++) xv[i] = ((const float4*)xsh)[(ci4 * 4 + i) * 64 + ng];
#pragma unroll
      for (int c = 0; c < 4; c++)
#pragma unroll
        for (int i = 0; i < 4; i++) {
          float wvc = i == 0 ? wv[c].x : i == 1 ? wv[c].y : i == 2 ? wv[c].z : wv[c].w;
          acc4[c].x += wvc * xv[i].x;
          acc4[c].y += wvc * xv[i].y;
          acc4[c].z += wvc * xv[i].z;
          acc4[c].w += wvc * xv[i].w;
        }
    }
    __syncthreads();
  }
#pragma unroll
  for (int c = 0; c < 4; c++) {
    int co = co0 + cg * 4 + c;
    ((float4*)(out + ((size_t)b * CO + co) * 1024 + nn0))[ng] = acc4[c];
  }
}

// ---------------------------------------------------------------------------
// 1x1 conv variant writing bf16 output [b][co][n] (MFMA A-operand row layout)
__global__ __launch_bounds__(256) void k_conv1x1_bf16(
    const float* __restrict__ xin, const float* __restrict__ w,
    const float* __restrict__ bias, const int* __restrict__ sidx,
    unsigned short* __restrict__ out, int CO) {
  __shared__ float xsh[32 * 256];
  __shared__ float wsh[16 * 32];
  const int t = threadIdx.x;
  const int b = blockIdx.x;
  const int cow = blockIdx.y >> 2, nw = blockIdx.y & 3;
  const int co0 = cow * 16, nn0 = nw * 256;
  const int s = sidx[b];
  const int cg = t >> 6, ng = t & 63;
  const float* xb = xin + (size_t)b * 128 * 1024;
  float4 acc4[4];
#pragma unroll
  for (int c = 0; c < 4; c++) {
    float bb = bias[s * CO + co0 + cg * 4 + c];
    acc4[c] = make_float4(bb, bb, bb, bb);
  }
  for (int cc = 0; cc < 4; cc++) {
#pragma unroll
    for (int k = 0; k < 8; k++) {
      int id = t + (k << 8);
      int ci = id >> 6, nf = id & 63;
      ((float4*)xsh)[id] = ((const float4*)(xb + (cc * 32 + ci) * 1024 + nn0))[nf];
    }
    if (t < 128)
      ((float4*)wsh)[t] =
          ((const float4*)(w + ((size_t)(s * CO + co0 + (t >> 3))) * 128 + cc * 32))[t & 7];
    __syncthreads();
#pragma unroll
    for (int ci4 = 0; ci4 < 8; ci4++) {
      float4 wv[4], xv[4];
#pragma unroll
      for (int c = 0; c < 4; c++) wv[c] = ((const float4*)wsh)[(cg * 4 + c) * 8 + ci4];
#pragma unroll
      for (int i = 0; i < 4; i++) xv[i] = ((const float4*)xsh)[(ci4 * 4 + i) * 64 + ng];
#pragma unroll
      for (int c = 0; c < 4; c++)
#pragma unroll
        for (int i = 0; i < 4; i++) {
          float wvc = i == 0 ? wv[c].x : i == 1 ? wv[c].y : i == 2 ? wv[c].z : wv[c].w;
          acc4[c].x += wvc * xv[i].x;
          acc4[c].y += wvc * xv[i].y;
          acc4[c].z += wvc * xv[i].z;
          acc4[c].w += wvc * xv[i].w;
        }
    }
    __syncthreads();
  }
#pragma unroll
  for (int c = 0; c < 4; c++) {
    int co = co0 + cg * 4 + c;
    bf16x4 u;
    u[0] = f2bf(acc4[c].x);
    u[1] = f2bf(acc4[c].y);
    u[2] = f2bf(acc4[c].z);
    u[3] = f2bf(acc4[c].w);
    *(bf16x4*)(out + ((size_t)b * CO + co) * 1024 + nn0 + ng * 4) = u;
  }
}

// ---------------------------------------------------------------------------
// fused self-attention, MFMA PV with barrier-free inner loop.
// grid (B*64): b = bx>>6, n-tile 16 = (bx&63)*16.
// Scores fp32 VALU; softmax via shuffle+LDS; P unnormalized bf16 in LDS
// ([nl][m-contig] B-operand layout); V read as bf16 DIRECTLY from global
// (precomputed by k_conv1x1_bf16, [co][m] = A-operand row layout).
__global__ __launch_bounds__(256) void k_attn(
    const float* __restrict__ q, const float* __restrict__ k,
    const unsigned short* __restrict__ v, const float* __restrict__ x1,
    const float* __restrict__ gamma, const int* __restrict__ sidx,
    float* __restrict__ y) {
  __shared__ __align__(16) short Psh[16 * 1032];  // 33 KB bf16 P^T [nl][m]
  __shared__ float qsh[256];                      // [c][nl]
  __shared__ float redm[64], reds[64];
  const int t = threadIdx.x;
  const int b = blockIdx.x >> 6;
  const int n0 = (blockIdx.x & 63) << 4;
  const int lane = t & 63, wv = t >> 6;
  const int quad = lane >> 4, l16 = lane & 15;
  const float* qb = q + (size_t)b * 16 * 1024;
  const float* kb = k + (size_t)b * 16 * 1024;
  const unsigned short* vb = v + (size_t)b * 128 * 1024;
  const float* xb = x1 + (size_t)b * 128 * 1024;

  qsh[t] = qb[((t >> 4) << 10) + n0 + (t & 15)];
  __syncthreads();

  // ---- scores: thread handles m = 4t..4t+3, all 16 nl
  float acc[4][16];
#pragma unroll
  for (int j = 0; j < 4; j++)
#pragma unroll
    for (int nl = 0; nl < 16; nl++) acc[j][nl] = 0.0f;
#pragma unroll
  for (int c = 0; c < 16; c++) {
    float4 kv = *(const float4*)(kb + (c << 10) + 4 * t);
    const float* qr = qsh + c * 16;
#pragma unroll
    for (int j = 0; j < 4; j++) {
      float kk = j == 0 ? kv.x : j == 1 ? kv.y : j == 2 ? kv.z : kv.w;
#pragma unroll
      for (int nl = 0; nl < 16; nl++) acc[j][nl] += kk * qr[nl];
    }
  }
  // ---- per-nl max over all m
  float lmax[16];
#pragma unroll
  for (int nl = 0; nl < 16; nl++)
    lmax[nl] = fmaxf(fmaxf(acc[0][nl], acc[1][nl]), fmaxf(acc[2][nl], acc[3][nl]));
#pragma unroll
  for (int o = 32; o > 0; o >>= 1)
#pragma unroll
    for (int nl = 0; nl < 16; nl++) lmax[nl] = fmaxf(lmax[nl], __shfl_xor(lmax[nl], o, 64));
  if (lane == 0)
#pragma unroll
    for (int nl = 0; nl < 16; nl++) redm[wv * 16 + nl] = lmax[nl];
  __syncthreads();
#pragma unroll
  for (int nl = 0; nl < 16; nl++)
    lmax[nl] = fmaxf(fmaxf(redm[nl], redm[16 + nl]), fmaxf(redm[32 + nl], redm[48 + nl]));
  // ---- exp (unnormalized) + per-nl sum
  float lsum[16];
#pragma unroll
  for (int nl = 0; nl < 16; nl++) lsum[nl] = 0.0f;
#pragma unroll
  for (int j = 0; j < 4; j++)
#pragma unroll
    for (int nl = 0; nl < 16; nl++) {
      float e = __expf(acc[j][nl] - lmax[nl]);
      acc[j][nl] = e;
      lsum[nl] += e;
    }
#pragma unroll
  for (int o = 32; o > 0; o >>= 1)
#pragma unroll
    for (int nl = 0; nl < 16; nl++) lsum[nl] += __shfl_xor(lsum[nl], o, 64);
  if (lane == 0)
#pragma unroll
    for (int nl = 0; nl < 16; nl++) reds[wv * 16 + nl] = lsum[nl];
  // ---- write P^T bf16 (m-contig per nl row)
#pragma unroll
  for (int nl = 0; nl < 16; nl++) {
    bf16x4 pv;
    pv[0] = f2bf(acc[0][nl]);
    pv[1] = f2bf(acc[1][nl]);
    pv[2] = f2bf(acc[2][nl]);
    pv[3] = f2bf(acc[3][nl]);
    *(bf16x4*)&Psh[nl * 1032 + 4 * t] = pv;
  }
  __syncthreads();

  // ---- PV: barrier-free. Wave wv owns co rows wv*32+l16 and +16.
  const unsigned short* a0p = vb + ((size_t)(wv * 32 + l16) << 10) + quad * 8;
  const unsigned short* a1p = a0p + (16 << 10);
  const short* prow = Psh + l16 * 1032 + quad * 8;
  f32x4 dacc[2];
  dacc[0] = (f32x4){0.f, 0.f, 0.f, 0.f};
  dacc[1] = (f32x4){0.f, 0.f, 0.f, 0.f};
#pragma unroll 4
  for (int mt = 0; mt < 1024; mt += 32) {
    bf16x8 af0 = *(const bf16x8*)(a0p + mt);
    bf16x8 af1 = *(const bf16x8*)(a1p + mt);
    bf16x8 bfr = *(const bf16x8*)(prow + mt);
    dacc[0] = __builtin_amdgcn_mfma_f32_16x16x32_bf16(af0, bfr, dacc[0], 0, 0, 0);
    dacc[1] = __builtin_amdgcn_mfma_f32_16x16x32_bf16(af1, bfr, dacc[1], 0, 0, 0);
  }
  // ---- epilogue: normalize, gamma, residual. C/D: col(n)=l16, row=quad*4+r
  float g = gamma[sidx[b]];
  float rs = 1.0f / (reds[l16] + reds[16 + l16] + reds[32 + l16] + reds[48 + l16]);
  int n = n0 + l16;
#pragma unroll
  for (int i = 0; i < 2; i++) {
    int cob = wv * 32 + i * 16 + quad * 4;
#pragma unroll
    for (int r = 0; r < 4; r++) {
      int co = cob + r;
      y[(((size_t)b * 128 + co) << 10) + n] = g * dacc[i][r] * rs + xb[(co << 10) + n];
    }
  }
}

// ---------------------------------------------------------------------------
// head: x2 (B,256,16,16) -> out (B,1,15,15), k4 s1 p1, +bias
__global__ __launch_bounds__(256) void k_head(
    const float* __restrict__ x2, const float* __restrict__ wh,
    const float* __restrict__ bh, const int* __restrict__ sidx,
    float* __restrict__ out) {
  int bp = blockIdx.x;
  int b = bp / 225, pix = bp % 225;
  int oh = pix / 15, ow = pix % 15;
  int s = sidx[b];
  int ci = threadIdx.x;
  const float* xp = x2 + (((size_t)b * 256 + ci) << 8);
  const float* wp = wh + s * 4096 + ci * 16;
  float acc = 0.0f;
#pragma unroll
  for (int kh = 0; kh < 4; kh++) {
    int ih = oh - 1 + kh;
    if ((unsigned)ih >= 16u) continue;
#pragma unroll
    for (int kw = 0; kw < 4; kw++) {
      int iw = ow - 1 + kw;
      if ((unsigned)iw >= 16u) continue;
      acc += wp[kh * 4 + kw] * xp[(ih << 4) + iw];
    }
  }
#pragma unroll
  for (int o = 32; o > 0; o >>= 1) acc += __shfl_down(acc, o, 64);
  __shared__ float red[4];
  if ((threadIdx.x & 63) == 0) red[threadIdx.x >> 6] = acc;
  __syncthreads();
  if (threadIdx.x == 0) {
    float r = red[0] + red[1] + red[2] + red[3] + bh[s];
    out[b * 225 + pix] = r;
  }
}

// ---------------------------------------------------------------------------
extern "C" void kernel_launch(void* const* d_in, const int* in_sizes, int n_in,
                              void* d_out, int out_size, void* d_ws, size_t ws_size,
                              hipStream_t stream) {
  const float* img = (const float*)d_in[0];
  const int* sidx = (const int*)d_in[1];
  const float* w0 = (const float*)d_in[2];
  const float* b0 = (const float*)d_in[3];
  const float* w1 = (const float*)d_in[4];
  const float* w2 = (const float*)d_in[6];
  const float* wq = (const float*)d_in[8];
  const float* bq = (const float*)d_in[9];
  const float* wk = (const float*)d_in[10];
  const float* bk = (const float*)d_in[11];
  const float* wv = (const float*)d_in[12];
  const float* bv = (const float*)d_in[13];
  const float* gamma = (const float*)d_in[14];
  const float* wh = (const float*)d_in[15];
  const float* bh = (const float*)d_in[16];
  float* out = (float*)d_out;

  float* ws = (float*)d_ws;
  float* x0 = ws + 0;        // (B,64,64,64)
  float* x1 = ws + 4194304;  // (B,128,32,32)
  float* q = ws + 6291456;   // (B,16,1024)
  float* k = ws + 6553600;
  unsigned short* vbf = (unsigned short*)(ws + 6815744);  // (B,128,1024) bf16
  float* x2 = ws + 8912896;  // (B,256,16,16)
  float* y = x0;             // alias, x0 dead after conv1

  const int B = 16;

  k_conv0<<<dim3(B * 64, 16), 256, 0, stream>>>(img, w0, b0, sidx, x0);
  k_conv_mfma<64, 128, 64, 5><<<dim3(B, 32), 256, 0, stream>>>(x0, w1, sidx, x1);
  k_inorm<1024><<<B * 128, 256, 0, stream>>>(x1);
  k_conv1x1<<<dim3(B, 4), 256, 0, stream>>>(x1, wq, bq, sidx, q, 16);
  k_conv1x1<<<dim3(B, 4), 256, 0, stream>>>(x1, wk, bk, sidx, k, 16);
  k_conv1x1_bf16<<<dim3(B, 32), 256, 0, stream>>>(x1, wv, bv, sidx, vbf, 128);
  k_attn<<<B * 64, 256, 0, stream>>>(q, k, vbf, x1, gamma, sidx, y);
  k_conv_mfma<128, 256, 32, 4><<<dim3(B, 16), 256, 0, stream>>>(y, w2, sidx, x2);
  k_inorm<256><<<B * 256, 256, 0, stream>>>(x2);
  k_head<<<B * 225, 256, 0, stream>>>(x2, wh, bh, sidx, out);
}

// Round 8
// 261.301 us; speedup vs baseline: 10.3600x; 1.5039x over previous
//
#include <hip/hip_runtime.h>

#define LRELU(x) ((x) > 0.0f ? (x) : 0.2f * (x))

typedef short bf16x8 __attribute__((ext_vector_type(8)));
typedef short bf16x4 __attribute__((ext_vector_type(4)));
typedef float f32x4 __attribute__((ext_vector_type(4)));

__device__ __forceinline__ short f2bf(float f) {
  union { float f; unsigned u; } x{f};
  return (short)((x.u + 0x7FFF + ((x.u >> 16) & 1)) >> 16);
}

// ---------------------------------------------------------------------------
// weight repack: w[s][co][ci][tap] fp32 -> wr[s][co][tap*CI+ci] bf16
__global__ __launch_bounds__(256) void k_repack(
    const float* __restrict__ w, unsigned short* __restrict__ wr, int CO, int CI,
    int total) {
  int idx = blockIdx.x * 256 + threadIdx.x;
  if (idx >= total) return;
  int K = CI * 16;
  int k = idx % K;
  int rest = idx / K;
  int co = rest % CO, s = rest / CO;
  int tap = k / CI, ci = k % CI;
  wr[idx] = (unsigned short)f2bf(w[((size_t)(s * CO + co) * CI + ci) * 16 + tap]);
}

// ---------------------------------------------------------------------------
// conv0: img (B,1,128,128) -> x0t NHWC bf16 (B,64*64,64), k4 s2 p1, bias+leaky
// grid (B, 256): 16-pixel tile (one oh row segment); thread = co(64) x 4 pix
__global__ __launch_bounds__(256) void k_conv0(
    const float* __restrict__ img, const float* __restrict__ w0,
    const float* __restrict__ b0, const int* __restrict__ sidx,
    unsigned short* __restrict__ x0t) {
  __shared__ float Ish[4 * 34];
  const int t = threadIdx.x;
  const int b = blockIdx.x;
  const int py = blockIdx.y;  // 0..255
  const int oh = py >> 2, owb = (py & 3) << 4;
  const int s = sidx[b];
  const float* ip = img + (size_t)b * 16384;
  if (t < 136) {
    int r = t / 34, c = t % 34;
    int ih = 2 * oh - 1 + r, iw = 2 * owb - 1 + c;
    Ish[t] = ((unsigned)ih < 128u && (unsigned)iw < 128u) ? ip[ih * 128 + iw] : 0.f;
  }
  const int co = t & 63, ps = t >> 6;
  float wr[16];
  const float* wp = w0 + (s * 64 + co) * 16;
#pragma unroll
  for (int i = 0; i < 16; i++) wr[i] = wp[i];
  float bb = b0[s * 64 + co];
  __syncthreads();
  unsigned short* op = x0t + ((size_t)b * 4096 + oh * 64 + owb) * 64 + co;
#pragma unroll
  for (int j = 0; j < 4; j++) {
    int pl = ps * 4 + j;  // pixel within 16-tile
    float acc = bb;
#pragma unroll
    for (int kh = 0; kh < 4; kh++)
#pragma unroll
      for (int kw = 0; kw < 4; kw++)
        acc += wr[kh * 4 + kw] * Ish[kh * 34 + pl * 2 + kw];
    acc = LRELU(acc);
    op[pl * 64] = (unsigned short)f2bf(acc);
  }
}

// ---------------------------------------------------------------------------
// MFMA implicit-GEMM k4s2p1 conv, NHWC bf16 in, packed bf16 weights, NCHW
// fp32 out (no bias - cancelled by inorm). K chunk = 32 (one tap ci-slice).
// grid (B, cotiles*ntiles, Z): Z splits K; dst = z ? out1 : out0.
template <int CI, int CO, int HIN, int OWSHIFT>
__global__ __launch_bounds__(256) void k_conv_nhwc(
    const unsigned short* __restrict__ xt, const unsigned short* __restrict__ wr,
    const int* __restrict__ sidx, float* __restrict__ out0, float* __restrict__ out1) {
  constexpr int WIN = HIN;
  constexpr int OW = 1 << OWSHIFT;
  constexpr int OH = HIN / 2;
  constexpr int NPB = OH * OW;
  constexpr int NT = NPB / 64;
  constexpr int CPT = CI / 32;  // chunks per tap
  __shared__ __align__(16) short Ash[64 * 40];
  __shared__ __align__(16) short Bsh[64 * 40];
  const int t = threadIdx.x;
  const int b = blockIdx.x;
  const int co0 = (blockIdx.y / NT) * 64;
  const int n0 = (blockIdx.y % NT) * 64;
  const int totkc = CI / 2;
  const int nkc = totkc / gridDim.z;
  const int kcb = blockIdx.z * nkc;
  float* dst = blockIdx.z ? out1 : out0;
  const int s = sidx[b];
  const int lane = t & 63, wv = t >> 6;
  const int wm = (wv >> 1) * 32, wn = (wv & 1) * 32;
  const int quad = lane >> 4, l16 = lane & 15;

  const int row = t & 63, grp = t >> 6;
  const unsigned short* arow = wr + (size_t)(s * CO + co0 + row) * (CI * 16) + grp * 8;
  const int p = n0 + row;
  const int oh = p >> OWSHIFT, ow = p & (OW - 1);
  const int ihb = 2 * oh - 1, iwb = 2 * ow - 1;
  const unsigned short* xb = xt + (size_t)b * (HIN * WIN) * CI;

  f32x4 acc[2][2];
#pragma unroll
  for (int i = 0; i < 2; i++)
#pragma unroll
    for (int j = 0; j < 2; j++) acc[i][j] = (f32x4){0.f, 0.f, 0.f, 0.f};

  for (int kk = 0; kk < nkc; kk++) {
    int kc = kcb + kk;
    // A: contiguous packed weights
    bf16x8 av = *(const bf16x8*)(arow + kc * 32);
    // B: one tap's 8-ci slice, direct NHWC vector load
    int tap = kc / CPT;
    int ci0 = (kc % CPT) * 32 + grp * 8;
    int kh = tap >> 2, kw = tap & 3;
    int ih = ihb + kh, iw = iwb + kw;
    bf16x8 bv = {0, 0, 0, 0, 0, 0, 0, 0};
    if ((unsigned)ih < (unsigned)HIN && (unsigned)iw < (unsigned)WIN)
      bv = *(const bf16x8*)(xb + ((size_t)(ih * WIN + iw)) * CI + ci0);
    *(bf16x8*)&Ash[row * 40 + grp * 8] = av;
    *(bf16x8*)&Bsh[row * 40 + grp * 8] = bv;
    __syncthreads();
    bf16x8 af[2], bfv[2];
#pragma unroll
    for (int i = 0; i < 2; i++)
      af[i] = *(const bf16x8*)&Ash[(wm + i * 16 + l16) * 40 + quad * 8];
#pragma unroll
    for (int j = 0; j < 2; j++)
      bfv[j] = *(const bf16x8*)&Bsh[(wn + j * 16 + l16) * 40 + quad * 8];
#pragma unroll
    for (int i = 0; i < 2; i++)
#pragma unroll
      for (int j = 0; j < 2; j++)
        acc[i][j] = __builtin_amdgcn_mfma_f32_16x16x32_bf16(af[i], bfv[j], acc[i][j], 0, 0, 0);
    __syncthreads();
  }
#pragma unroll
  for (int i = 0; i < 2; i++) {
    int cobase = co0 + wm + i * 16 + quad * 4;
#pragma unroll
    for (int j = 0; j < 2; j++) {
      int n = n0 + wn + j * 16 + l16;
#pragma unroll
      for (int r = 0; r < 4; r++)
        dst[((size_t)b * CO + cobase + r) * NPB + n] = acc[i][j][r];
    }
  }
}

// ---------------------------------------------------------------------------
// instance norm (+leaky) in place, NPIX=1024
template <int NPIX>
__global__ __launch_bounds__(256) void k_inorm(float* __restrict__ x) {
  float* p = x + (size_t)blockIdx.x * NPIX;
  float sum = 0.0f, sq = 0.0f;
  for (int i = threadIdx.x; i < NPIX; i += 256) {
    float v = p[i];
    sum += v;
    sq += v * v;
  }
#pragma unroll
  for (int o = 32; o > 0; o >>= 1) {
    sum += __shfl_down(sum, o, 64);
    sq += __shfl_down(sq, o, 64);
  }
  __shared__ float red[8];
  int wid = threadIdx.x >> 6;
  if ((threadIdx.x & 63) == 0) {
    red[wid] = sum;
    red[4 + wid] = sq;
  }
  __syncthreads();
  if (threadIdx.x == 0) {
    red[0] = red[0] + red[1] + red[2] + red[3];
    red[4] = red[4] + red[5] + red[6] + red[7];
  }
  __syncthreads();
  float m = red[0] * (1.0f / NPIX);
  float var = red[4] * (1.0f / NPIX) - m * m;
  float inv = rsqrtf(var + 1e-5f);
  for (int i = threadIdx.x; i < NPIX; i += 256) {
    float v = (p[i] - m) * inv;
    p[i] = LRELU(v);
  }
}

// ---------------------------------------------------------------------------
// fused sum + instance norm (+leaky): o = lrelu(inorm(a+b)), NPIX=256,
// one elem per thread, block per (b,c)
__global__ __launch_bounds__(256) void k_inorm2(
    const float* __restrict__ a, const float* __restrict__ b, float* __restrict__ o) {
  size_t base = (size_t)blockIdx.x * 256;
  size_t i = base + threadIdx.x;
  float v = a[i] + b[i];
  float sum = v, sq = v * v;
#pragma unroll
  for (int off = 32; off > 0; off >>= 1) {
    sum += __shfl_down(sum, off, 64);
    sq += __shfl_down(sq, off, 64);
  }
  __shared__ float red[8];
  int wid = threadIdx.x >> 6;
  if ((threadIdx.x & 63) == 0) {
    red[wid] = sum;
    red[4 + wid] = sq;
  }
  __syncthreads();
  float S = red[0] + red[1] + red[2] + red[3];
  float SQ = red[4] + red[5] + red[6] + red[7];
  float m = S * (1.0f / 256.0f);
  float var = SQ * (1.0f / 256.0f) - m * m;
  float inv = rsqrtf(var + 1e-5f);
  float r = (v - m) * inv;
  o[i] = LRELU(r);
}

// ---------------------------------------------------------------------------
// 1x1 conv, register-tiled GEMM, fp32 out
__global__ __launch_bounds__(256) void k_conv1x1(
    const float* __restrict__ xin, const float* __restrict__ w,
    const float* __restrict__ bias, const int* __restrict__ sidx,
    float* __restrict__ out, int CO) {
  __shared__ float xsh[32 * 256];
  __shared__ float wsh[16 * 32];
  const int t = threadIdx.x;
  const int b = blockIdx.x;
  const int cow = blockIdx.y >> 2, nw = blockIdx.y & 3;
  const int co0 = cow * 16, nn0 = nw * 256;
  const int s = sidx[b];
  const int cg = t >> 6, ng = t & 63;
  const float* xb = xin + (size_t)b * 128 * 1024;
  float4 acc4[4];
#pragma unroll
  for (int c = 0; c < 4; c++) {
    float bb = bias[s * CO + co0 + cg * 4 + c];
    acc4[c] = make_float4(bb, bb, bb, bb);
  }
  for (int cc = 0; cc < 4; cc++) {
#pragma unroll
    for (int k = 0; k < 8; k++) {
      int id = t + (k << 8);
      int ci = id >> 6, nf = id & 63;
      ((float4*)xsh)[id] = ((const float4*)(xb + (cc * 32 + ci) * 1024 + nn0))[nf];
    }
    if (t < 128)
      ((float4*)wsh)[t] =
          ((const float4*)(w + ((size_t)(s * CO + co0 + (t >> 3))) * 128 + cc * 32))[t & 7];
    __syncthreads();
#pragma unroll
    for (int ci4 = 0; ci4 < 8; ci4++) {
      float4 wv[4], xv[4];
#pragma unroll
      for (int c = 0; c < 4; c++) wv[c] = ((const float4*)wsh)[(cg * 4 + c) * 8 + ci4];
#pragma unroll
      for (int i = 0; i < 4; i++) xv[i] = ((const float4*)xsh)[(ci4 * 4 + i) * 64 + ng];
#pragma unroll
      for (int c = 0; c < 4; c++)
#pragma unroll
        for (int i = 0; i < 4; i++) {
          float wvc = i == 0 ? wv[c].x : i == 1 ? wv[c].y : i == 2 ? wv[c].z : wv[c].w;
          acc4[c].x += wvc * xv[i].x;
          acc4[c].y += wvc * xv[i].y;
          acc4[c].z += wvc * xv[i].z;
          acc4[c].w += wvc * xv[i].w;
        }
    }
    __syncthreads();
  }
#pragma unroll
  for (int c = 0; c < 4; c++) {
    int co = co0 + cg * 4 + c;
    ((float4*)(out + ((size_t)b * CO + co) * 1024 + nn0))[ng] = acc4[c];
  }
}

// ---------------------------------------------------------------------------
// 1x1 conv variant writing bf16 output [b][co][n] (MFMA A-operand row layout)
__global__ __launch_bounds__(256) void k_conv1x1_bf16(
    const float* __restrict__ xin, const float* __restrict__ w,
    const float* __restrict__ bias, const int* __restrict__ sidx,
    unsigned short* __restrict__ out, int CO) {
  __shared__ float xsh[32 * 256];
  __shared__ float wsh[16 * 32];
  const int t = threadIdx.x;
  const int b = blockIdx.x;
  const int cow = blockIdx.y >> 2, nw = blockIdx.y & 3;
  const int co0 = cow * 16, nn0 = nw * 256;
  const int s = sidx[b];
  const int cg = t >> 6, ng = t & 63;
  const float* xb = xin + (size_t)b * 128 * 1024;
  float4 acc4[4];
#pragma unroll
  for (int c = 0; c < 4; c++) {
    float bb = bias[s * CO + co0 + cg * 4 + c];
    acc4[c] = make_float4(bb, bb, bb, bb);
  }
  for (int cc = 0; cc < 4; cc++) {
#pragma unroll
    for (int k = 0; k < 8; k++) {
      int id = t + (k << 8);
      int ci = id >> 6, nf = id & 63;
      ((float4*)xsh)[id] = ((const float4*)(xb + (cc * 32 + ci) * 1024 + nn0))[nf];
    }
    if (t < 128)
      ((float4*)wsh)[t] =
          ((const float4*)(w + ((size_t)(s * CO + co0 + (t >> 3))) * 128 + cc * 32))[t & 7];
    __syncthreads();
#pragma unroll
    for (int ci4 = 0; ci4 < 8; ci4++) {
      float4 wv[4], xv[4];
#pragma unroll
      for (int c = 0; c < 4; c++) wv[c] = ((const float4*)wsh)[(cg * 4 + c) * 8 + ci4];
#pragma unroll
      for (int i = 0; i < 4; i++) xv[i] = ((const float4*)xsh)[(ci4 * 4 + i) * 64 + ng];
#pragma unroll
      for (int c = 0; c < 4; c++)
#pragma unroll
        for (int i = 0; i < 4; i++) {
          float wvc = i == 0 ? wv[c].x : i == 1 ? wv[c].y : i == 2 ? wv[c].z : wv[c].w;
          acc4[c].x += wvc * xv[i].x;
          acc4[c].y += wvc * xv[i].y;
          acc4[c].z += wvc * xv[i].z;
          acc4[c].w += wvc * xv[i].w;
        }
    }
    __syncthreads();
  }
#pragma unroll
  for (int c = 0; c < 4; c++) {
    int co = co0 + cg * 4 + c;
    bf16x4 u;
    u[0] = f2bf(acc4[c].x);
    u[1] = f2bf(acc4[c].y);
    u[2] = f2bf(acc4[c].z);
    u[3] = f2bf(acc4[c].w);
    *(bf16x4*)(out + ((size_t)b * CO + co) * 1024 + nn0 + ng * 4) = u;
  }
}

// ---------------------------------------------------------------------------
// fused self-attention, MFMA PV, barrier-free inner loop; writes ybf NHWC bf16
// (gamma*out/sum + x1 residual folded). grid (B*64).
__global__ __launch_bounds__(256) void k_attn(
    const float* __restrict__ q, const float* __restrict__ k,
    const unsigned short* __restrict__ v, const float* __restrict__ x1,
    const float* __restrict__ gamma, const int* __restrict__ sidx,
    unsigned short* __restrict__ ybf) {
  __shared__ __align__(16) short Psh[16 * 1032];
  __shared__ float qsh[256];
  __shared__ float redm[64], reds[64];
  const int t = threadIdx.x;
  const int b = blockIdx.x >> 6;
  const int n0 = (blockIdx.x & 63) << 4;
  const int lane = t & 63, wv = t >> 6;
  const int quad = lane >> 4, l16 = lane & 15;
  const float* qb = q + (size_t)b * 16 * 1024;
  const float* kb = k + (size_t)b * 16 * 1024;
  const unsigned short* vb = v + (size_t)b * 128 * 1024;
  const float* xb = x1 + (size_t)b * 128 * 1024;

  qsh[t] = qb[((t >> 4) << 10) + n0 + (t & 15)];
  __syncthreads();

  float acc[4][16];
#pragma unroll
  for (int j = 0; j < 4; j++)
#pragma unroll
    for (int nl = 0; nl < 16; nl++) acc[j][nl] = 0.0f;
#pragma unroll
  for (int c = 0; c < 16; c++) {
    float4 kv = *(const float4*)(kb + (c << 10) + 4 * t);
    const float* qr = qsh + c * 16;
#pragma unroll
    for (int j = 0; j < 4; j++) {
      float kk = j == 0 ? kv.x : j == 1 ? kv.y : j == 2 ? kv.z : kv.w;
#pragma unroll
      for (int nl = 0; nl < 16; nl++) acc[j][nl] += kk * qr[nl];
    }
  }
  float lmax[16];
#pragma unroll
  for (int nl = 0; nl < 16; nl++)
    lmax[nl] = fmaxf(fmaxf(acc[0][nl], acc[1][nl]), fmaxf(acc[2][nl], acc[3][nl]));
#pragma unroll
  for (int o = 32; o > 0; o >>= 1)
#pragma unroll
    for (int nl = 0; nl < 16; nl++) lmax[nl] = fmaxf(lmax[nl], __shfl_xor(lmax[nl], o, 64));
  if (lane == 0)
#pragma unroll
    for (int nl = 0; nl < 16; nl++) redm[wv * 16 + nl] = lmax[nl];
  __syncthreads();
#pragma unroll
  for (int nl = 0; nl < 16; nl++)
    lmax[nl] = fmaxf(fmaxf(redm[nl], redm[16 + nl]), fmaxf(redm[32 + nl], redm[48 + nl]));
  float lsum[16];
#pragma unroll
  for (int nl = 0; nl < 16; nl++) lsum[nl] = 0.0f;
#pragma unroll
  for (int j = 0; j < 4; j++)
#pragma unroll
    for (int nl = 0; nl < 16; nl++) {
      float e = __expf(acc[j][nl] - lmax[nl]);
      acc[j][nl] = e;
      lsum[nl] += e;
    }
#pragma unroll
  for (int o = 32; o > 0; o >>= 1)
#pragma unroll
    for (int nl = 0; nl < 16; nl++) lsum[nl] += __shfl_xor(lsum[nl], o, 64);
  if (lane == 0)
#pragma unroll
    for (int nl = 0; nl < 16; nl++) reds[wv * 16 + nl] = lsum[nl];
#pragma unroll
  for (int nl = 0; nl < 16; nl++) {
    bf16x4 pv;
    pv[0] = f2bf(acc[0][nl]);
    pv[1] = f2bf(acc[1][nl]);
    pv[2] = f2bf(acc[2][nl]);
    pv[3] = f2bf(acc[3][nl]);
    *(bf16x4*)&Psh[nl * 1032 + 4 * t] = pv;
  }
  __syncthreads();

  const unsigned short* a0p = vb + ((size_t)(wv * 32 + l16) << 10) + quad * 8;
  const unsigned short* a1p = a0p + (16 << 10);
  const short* prow = Psh + l16 * 1032 + quad * 8;
  f32x4 dacc[2];
  dacc[0] = (f32x4){0.f, 0.f, 0.f, 0.f};
  dacc[1] = (f32x4){0.f, 0.f, 0.f, 0.f};
#pragma unroll 4
  for (int mt = 0; mt < 1024; mt += 32) {
    bf16x8 af0 = *(const bf16x8*)(a0p + mt);
    bf16x8 af1 = *(const bf16x8*)(a1p + mt);
    bf16x8 bfr = *(const bf16x8*)(prow + mt);
    dacc[0] = __builtin_amdgcn_mfma_f32_16x16x32_bf16(af0, bfr, dacc[0], 0, 0, 0);
    dacc[1] = __builtin_amdgcn_mfma_f32_16x16x32_bf16(af1, bfr, dacc[1], 0, 0, 0);
  }
  float g = gamma[sidx[b]];
  float rs = 1.0f / (reds[l16] + reds[16 + l16] + reds[32 + l16] + reds[48 + l16]);
  int n = n0 + l16;
  unsigned short* yp = ybf + ((size_t)b * 1024 + n) * 128;
#pragma unroll
  for (int i = 0; i < 2; i++) {
    int cob = wv * 32 + i * 16 + quad * 4;
    bf16x4 u;
#pragma unroll
    for (int r = 0; r < 4; r++) {
      int co = cob + r;
      u[r] = f2bf(g * dacc[i][r] * rs + xb[(co << 10) + n]);
    }
    *(bf16x4*)(yp + cob) = u;
  }
}

// ---------------------------------------------------------------------------
// head: init out with bias, then partial conv via LDS + atomicAdd
__global__ __launch_bounds__(256) void k_head_init(
    const float* __restrict__ bh, const int* __restrict__ sidx, float* __restrict__ out) {
  int i = blockIdx.x * 256 + threadIdx.x;
  if (i < 3600) out[i] = bh[sidx[i / 225]];
}

__global__ __launch_bounds__(256) void k_head_part(
    const float* __restrict__ x2, const float* __restrict__ wh,
    const int* __restrict__ sidx, float* __restrict__ out) {
  __shared__ float Xs[32 * 256];
  __shared__ float Wsh[512];
  const int t = threadIdx.x;
  const int b = blockIdx.x, cc = blockIdx.y;  // cc 0..7
  const int s = sidx[b];
  const float* xp = x2 + ((size_t)b * 256 + cc * 32) * 256;
#pragma unroll
  for (int i = 0; i < 32; i++) Xs[i * 256 + t] = xp[i * 256 + t];
#pragma unroll
  for (int i = 0; i < 2; i++) {
    int idx = i * 256 + t;
    Wsh[idx] = wh[s * 4096 + cc * 512 + idx];
  }
  __syncthreads();
  if (t < 225) {
    int oh = t / 15, ow = t % 15;
    float acc = 0.0f;
    for (int ci = 0; ci < 32; ci++) {
      const float* xr = Xs + ci * 256;
      const float* wr = Wsh + ci * 16;
#pragma unroll
      for (int kh = 0; kh < 4; kh++) {
        int ih = oh - 1 + kh;
        if ((unsigned)ih >= 16u) continue;
#pragma unroll
        for (int kw = 0; kw < 4; kw++) {
          int iw = ow - 1 + kw;
          if ((unsigned)iw >= 16u) continue;
          acc += wr[kh * 4 + kw] * xr[(ih << 4) + iw];
        }
      }
    }
    atomicAdd(out + b * 225 + t, acc);
  }
}

// ---------------------------------------------------------------------------
extern "C" void kernel_launch(void* const* d_in, const int* in_sizes, int n_in,
                              void* d_out, int out_size, void* d_ws, size_t ws_size,
                              hipStream_t stream) {
  const float* img = (const float*)d_in[0];
  const int* sidx = (const int*)d_in[1];
  const float* w0 = (const float*)d_in[2];
  const float* b0 = (const float*)d_in[3];
  const float* w1 = (const float*)d_in[4];
  const float* w2 = (const float*)d_in[6];
  const float* wq = (const float*)d_in[8];
  const float* bq = (const float*)d_in[9];
  const float* wk = (const float*)d_in[10];
  const float* bk = (const float*)d_in[11];
  const float* wv = (const float*)d_in[12];
  const float* bv = (const float*)d_in[13];
  const float* gamma = (const float*)d_in[14];
  const float* wh = (const float*)d_in[15];
  const float* bh = (const float*)d_in[16];
  float* out = (float*)d_out;

  float* ws = (float*)d_ws;
  // layout (float offsets):
  unsigned short* x0t = (unsigned short*)(ws);           // [0, 2M) B*4096*64 bf16
  float* x1 = ws + 2097152;                              // [2M, 4M)
  float* q = ws + 4194304;                               // 256K
  float* k = ws + 4456448;                               // 256K
  unsigned short* vbf = (unsigned short*)(ws + 4718592); // 1M floats span
  unsigned short* ybf = (unsigned short*)(ws + 5767168); // 1M floats span
  float* x2a = ws + 6815744;                             // 1M
  float* x2b = ws + 7864320;                             // 1M
  unsigned short* wr1 = (unsigned short*)(ws + 8912896); // 256K floats span
  unsigned short* wr2 = (unsigned short*)(ws + 9175040); // 1M floats span

  const int B = 16;

  k_repack<<<2048, 256, 0, stream>>>(w1, wr1, 128, 64, 524288);
  k_repack<<<8192, 256, 0, stream>>>(w2, wr2, 256, 128, 2097152);
  k_conv0<<<dim3(B, 256), 256, 0, stream>>>(img, w0, b0, sidx, x0t);
  k_conv_nhwc<64, 128, 64, 5><<<dim3(B, 32, 1), 256, 0, stream>>>(x0t, wr1, sidx, x1, x1);
  k_inorm<1024><<<B * 128, 256, 0, stream>>>(x1);
  k_conv1x1<<<dim3(B, 4), 256, 0, stream>>>(x1, wq, bq, sidx, q, 16);
  k_conv1x1<<<dim3(B, 4), 256, 0, stream>>>(x1, wk, bk, sidx, k, 16);
  k_conv1x1_bf16<<<dim3(B, 32), 256, 0, stream>>>(x1, wv, bv, sidx, vbf, 128);
  k_attn<<<B * 64, 256, 0, stream>>>(q, k, vbf, x1, gamma, sidx, ybf);
  k_conv_nhwc<128, 256, 32, 4><<<dim3(B, 16, 2), 256, 0, stream>>>(ybf, wr2, sidx, x2a, x2b);
  k_inorm2<<<B * 256, 256, 0, stream>>>(x2a, x2b, x2a);
  k_head_init<<<15, 256, 0, stream>>>(bh, sidx, out);
  k_head_part<<<dim3(B, 8), 256, 0, stream>>>(x2a, wh, sidx, out);
}